// Round 17
// baseline (132.728 us; speedup 1.0000x reference)
//
#include <hip/hip_runtime.h>
#include <hip/hip_bf16.h>
#include <cstdint>
#include <cstddef>

#define DIM   1024
#define INTER 1024
#define NT    2048      // tokens

typedef __attribute__((ext_vector_type(4))) float  f32x4;
typedef __attribute__((ext_vector_type(8))) short  s16x8;
typedef __attribute__((ext_vector_type(8))) unsigned short u16x8;

// workspace layout (bytes)
#define WS_CNT    0u          // cnt[0..7]=counts, [8..16]=offsets, [17]=ntiles
#define WS_SLOT   256u        // slots[4096] = 16384 B
#define WS_TTAB   16640u      // m-tile table, <=56 ints (spare space in slots region)
#define WS_ASSIGN 33024u
#define WS_WT     65792u
#define WS_WTS2   98560u
#define WS_XB     131584u     // [2048][1024] bf16
#define WS_H      4325888u    // [6144][1024] bf16
#define WS_W1T    16908800u   // frag-linear bf16 weights; obuf after kfat2
#define WS_W3T    33686016u
#define WS_W2T    50463232u
#define WS_SW1T   67240448u
#define WS_SW3T   69337600u
#define WS_SW2T   71434752u
#define WS_NEED   73531904u
#define WS_OBUF   WS_W1T

__device__ __forceinline__ unsigned short f2bf(float f) {
    unsigned int u = __float_as_uint(f);
    return (unsigned short)((u + 0x7fffu + ((u >> 16) & 1u)) >> 16);
}
__device__ __forceinline__ float bf2f(unsigned short v) {
    return __uint_as_float(((unsigned int)v) << 16);
}

__device__ __forceinline__ void cp16(const void* g, void* l) {
    __builtin_amdgcn_global_load_lds((const __attribute__((address_space(1))) void*)g,
                                     (__attribute__((address_space(3))) void*)l, 16, 0, 0);
}

// ---------------- fat1: conv(w1,w3,sw1,sw3) [blocks 0..2303] + gate [2304..2815] ----------------
__global__ __launch_bounds__(256) void kfat1(
    const float* __restrict__ x, const float* __restrict__ gw,
    const float* __restrict__ w1, const float* __restrict__ w3,
    const float* __restrict__ sw1, const float* __restrict__ sw3,
    unsigned short* __restrict__ w1t, unsigned short* __restrict__ w3t,
    unsigned short* __restrict__ sw1t, unsigned short* __restrict__ sw3t,
    int* __restrict__ assign, float2* __restrict__ wts2, unsigned short* __restrict__ xb)
{
    __shared__ __align__(16) char smem[32768];
    int bid = blockIdx.x;
    int tid = threadIdx.x;
    if (bid < 2304) {
        int slab = bid >> 7, t = bid & 127;
        int r0 = (t >> 3) * 64, c0 = (t & 7) * 128;
        const float* src; unsigned short* dst;
        if (slab < 8)        { src = w1 + (size_t)slab * DIM * INTER;       dst = w1t + (size_t)slab * DIM * INTER; }
        else if (slab < 16)  { src = w3 + (size_t)(slab - 8) * DIM * INTER; dst = w3t + (size_t)(slab - 8) * DIM * INTER; }
        else if (slab == 16) { src = sw1; dst = sw1t; }
        else                 { src = sw3; dst = sw3t; }

        int w = tid >> 6, l = tid & 63;
        size_t lanoff = (size_t)(l >> 5) * 4096 + (size_t)(l & 31) * 16;
        const char* gbase = (const char*)src + (size_t)r0 * 4096 + (size_t)c0 * 4;
        #pragma unroll
        for (int i = 0; i < 8; ++i)
            cp16(gbase + (size_t)(w * 16 + i * 2) * 4096 + lanoff, smem + (w * 16 + i * 2) * 512);
        asm volatile("s_waitcnt vmcnt(0)" ::: "memory");
        __builtin_amdgcn_sched_barrier(0);
        __builtin_amdgcn_s_barrier();
        __builtin_amdgcn_sched_barrier(0);
        const float* ldsf = (const float*)smem;
        #pragma unroll
        for (int i = 0; i < 4; ++i) {
            int f = w * 4 + i;
            int ntl = f >> 1, ktl = f & 1;
            u16x8 o;
            #pragma unroll
            for (int j = 0; j < 8; ++j)
                o[j] = f2bf(ldsf[(ktl * 32 + (l >> 4) * 8 + j) * 128 + ntl * 16 + (l & 15)]);
            size_t off = ((size_t)((c0 >> 4) + ntl) * 32 + (r0 >> 5) + ktl) * 512 + l * 8;
            *(u16x8*)(dst + off) = o;
        }
        return;
    }
    // ---- gate ----
    int wid = tid >> 6, lane = tid & 63;
    int t = (bid - 2304) * 4 + wid;
    const float* xrow = x + (size_t)t * DIM;

    float xr[16];
    float acc[8] = {0.f,0.f,0.f,0.f,0.f,0.f,0.f,0.f};
    #pragma unroll
    for (int j = 0; j < 16; ++j) {
        float xv = xrow[j * 64 + lane];
        xr[j] = xv;
        const f32x4* g = (const f32x4*)(gw + (size_t)(j * 64 + lane) * 8);
        f32x4 g0 = g[0], g1 = g[1];
        acc[0] += xv * g0[0]; acc[1] += xv * g0[1]; acc[2] += xv * g0[2]; acc[3] += xv * g0[3];
        acc[4] += xv * g1[0]; acc[5] += xv * g1[1]; acc[6] += xv * g1[2]; acc[7] += xv * g1[3];
    }
    #pragma unroll
    for (int j = 0; j < 16; ++j) xb[(size_t)t * DIM + j * 64 + lane] = f2bf(xr[j]);

    #pragma unroll
    for (int e = 0; e < 8; ++e) {
        float v = acc[e];
        v += __shfl_xor(v, 1);  v += __shfl_xor(v, 2);  v += __shfl_xor(v, 4);
        v += __shfl_xor(v, 8);  v += __shfl_xor(v, 16); v += __shfl_xor(v, 32);
        acc[e] = v;
    }
    float mx = acc[0];
    #pragma unroll
    for (int e = 1; e < 8; ++e) mx = fmaxf(mx, acc[e]);
    float p[8]; float se = 0.f;
    #pragma unroll
    for (int e = 0; e < 8; ++e) { p[e] = expf(acc[e] - mx); se += p[e]; }
    float inv = 1.0f / se;
    int i0 = 0; float b0 = p[0];
    #pragma unroll
    for (int e = 1; e < 8; ++e) if (p[e] > b0) { b0 = p[e]; i0 = e; }
    int i1 = -1; float b1 = -1.f;
    #pragma unroll
    for (int e = 0; e < 8; ++e) if (e != i0 && p[e] > b1) { b1 = p[e]; i1 = e; }
    if (lane == 0) {
        assign[t] = i0 | (i1 << 8);
        wts2[t] = make_float2(b0 * inv, b1 * inv);
    }
}

// ---------------- scatter: compacted lists + dense m-tile table ----------------
__global__ __launch_bounds__(256) void kscatter(const int* __restrict__ assign,
                                                const float2* __restrict__ wts2,
                                                int* __restrict__ cnt,
                                                int* __restrict__ ttab,
                                                int* __restrict__ slots,
                                                float* __restrict__ wts)
{
    __shared__ int h[8], pos[8];
    int tid = threadIdx.x, lane = tid & 63;
    if (tid < 8) h[tid] = 0;
    __syncthreads();

    for (int base = 0; base < NT; base += 256) {
        int a = assign[base + tid];
        int e0 = a & 255, e1 = (a >> 8) & 255;
        #pragma unroll
        for (int e = 0; e < 8; ++e) {
            unsigned long long m0 = __ballot(e0 == e);
            unsigned long long m1 = __ballot(e1 == e);
            if (lane == 0) {
                int c = __popcll(m0) + __popcll(m1);
                if (c) atomicAdd(&h[e], c);
            }
        }
    }
    __syncthreads();
    if (tid == 0) {
        int run = 0;
        #pragma unroll
        for (int e = 0; e < 8; ++e) {
            cnt[8 + e] = run; pos[e] = run;
            cnt[e] = h[e]; run += h[e];
        }
        cnt[16] = run;
        // dense m-tile table (separate region -- does NOT overrun cnt)
        int ntt = 0;
        #pragma unroll
        for (int e = 0; e < 8; ++e)
            for (int m0 = 0; m0 < h[e]; m0 += 128) ttab[ntt++] = (e << 16) | m0;
        for (int m0 = 0; m0 < NT; m0 += 128) ttab[ntt++] = (8 << 16) | m0;
        cnt[17] = ntt;
    }
    __syncthreads();

    for (int base = 0; base < NT; base += 256) {
        int t = base + tid;
        int a = assign[t];
        float2 w = wts2[t];
        int e0 = a & 255, e1 = (a >> 8) & 255;
        unsigned long long lt = (1ull << lane) - 1ull;
        #pragma unroll
        for (int e = 0; e < 8; ++e) {
            unsigned long long m0 = __ballot(e0 == e);
            unsigned long long m1 = __ballot(e1 == e);
            int c = __popcll(m0) + __popcll(m1);
            int b = 0;
            if (lane == 0 && c) b = atomicAdd(&pos[e], c);
            b = __shfl(b, 0);
            if (e0 == e) { int r = __popcll(m0 & lt);                 slots[b + r] = t * 2;     wts[b + r] = w.x; }
            if (e1 == e) { int r = __popcll(m0) + __popcll(m1 & lt);  slots[b + r] = t * 2 + 1; wts[b + r] = w.y; }
        }
    }
}

// ---------------- fat2: 1-D compact grid. bid<1152: conv(w2,sw2); else GEMM1 ----------------
// GEMM1: BM=128 BN=64 BK=64; 4 waves 2x2. A LDS dbuf (cp16+swizzle); B depth-2
// register prefetch from frag-linear weights. Tile (e,m0) from dense table ->
// zero dead m-tile blocks (residency fix).
__global__ __launch_bounds__(256) void kfat2(
    const unsigned short* __restrict__ xb,
    const unsigned short* __restrict__ w1t, const unsigned short* __restrict__ w3t,
    const unsigned short* __restrict__ sw1t, const unsigned short* __restrict__ sw3t,
    const int* __restrict__ cnt, const int* __restrict__ ttab, const int* __restrict__ slots,
    unsigned short* __restrict__ hbuf,
    const float* __restrict__ w2, const float* __restrict__ sw2,
    unsigned short* __restrict__ w2t, unsigned short* __restrict__ sw2t)
{
    __shared__ __align__(16) char smem[34048];
    int bid = blockIdx.x;
    int tid = threadIdx.x;
    if (bid < 1152) {
        int slab = bid >> 7, t = bid & 127;
        const float* src; unsigned short* dst;
        if (slab < 8) { src = w2 + (size_t)slab * DIM * INTER; dst = w2t + (size_t)slab * DIM * INTER; }
        else          { src = sw2; dst = sw2t; }
        int r0 = (t >> 3) * 64, c0 = (t & 7) * 128;

        int w = tid >> 6, l = tid & 63;
        size_t lanoff = (size_t)(l >> 5) * 4096 + (size_t)(l & 31) * 16;
        const char* gbase = (const char*)src + (size_t)r0 * 4096 + (size_t)c0 * 4;
        #pragma unroll
        for (int i = 0; i < 8; ++i)
            cp16(gbase + (size_t)(w * 16 + i * 2) * 4096 + lanoff, smem + (w * 16 + i * 2) * 512);
        asm volatile("s_waitcnt vmcnt(0)" ::: "memory");
        __builtin_amdgcn_sched_barrier(0);
        __builtin_amdgcn_s_barrier();
        __builtin_amdgcn_sched_barrier(0);
        const float* ldsf = (const float*)smem;
        #pragma unroll
        for (int i = 0; i < 4; ++i) {
            int f = w * 4 + i;
            int ntl = f >> 1, ktl = f & 1;
            u16x8 o;
            #pragma unroll
            for (int j = 0; j < 8; ++j)
                o[j] = f2bf(ldsf[(ktl * 32 + (l >> 4) * 8 + j) * 128 + ntl * 16 + (l & 15)]);
            size_t off = ((size_t)((c0 >> 4) + ntl) * 32 + (r0 >> 5) + ktl) * 512 + l * 8;
            *(u16x8*)(dst + off) = o;
        }
        return;
    }

    int g = bid - 1152;
    int tile = g >> 4;
    if (tile >= cnt[17]) return;
    int info = ttab[tile];
    int e = info >> 16;
    int m0 = info & 0xffff;
    int n0 = (g & 15) * 64;
    int n_rows, lbase;
    if (e < 8) { n_rows = cnt[e]; lbase = cnt[8 + e]; } else { n_rows = NT; lbase = 0; }
    int rm = min(128, n_rows - m0);

    const unsigned short* b1p = (e < 8) ? (w1t + (size_t)e * DIM * INTER) : sw1t;
    const unsigned short* b3p = (e < 8) ? (w3t + (size_t)e * DIM * INTER) : sw3t;

    char* sA = smem;                       // [2][16384] A dbuf
    int* rowTok  = (int*)(smem + 32768);
    int* rowSlot = (int*)(smem + 33280);

    if (tid < 128) {
        int r = m0 + min(tid, rm - 1);
        int slot, tok;
        if (e < 8) { slot = slots[lbase + r]; tok = slot >> 1; }
        else       { tok = r; slot = 4096 + r; }
        rowTok[tid] = tok;
        rowSlot[tid] = slot;
    }
    __syncthreads();

    int wid = tid >> 6, lane = tid & 63;
    int wr = wid >> 1, wc = wid & 1;
    int swz_st = (((lane & 7) ^ (lane >> 3)) - (lane & 7)) * 16;

    const char* pA[4];
    #pragma unroll
    for (int q = 0; q < 4; ++q) {
        int row = (q * 4 + wid) * 8 + (lane >> 3);
        pA[q] = (const char*)(xb + (size_t)rowTok[row] * DIM) + (lane & 7) * 16 + swz_st;
    }
    const char* pB1[2]; const char* pB3[2];
    #pragma unroll
    for (int n = 0; n < 2; ++n) {
        int nt = (n0 >> 4) + wc * 2 + n;
        pB1[n] = (const char*)b1p + (size_t)nt * 32768 + lane * 16;
        pB3[n] = (const char*)b3p + (size_t)nt * 32768 + lane * 16;
    }

    int loA[2];
    #pragma unroll
    for (int ks = 0; ks < 2; ++ks) {
        int ch = ((ks * 4) + (lane >> 4)) ^ (lane & 7);
        loA[ks] = (wr * 64 + (lane & 15)) * 128 + ch * 16;
    }

    f32x4 acc1[4][2], acc3[4][2];
    #pragma unroll
    for (int m = 0; m < 4; ++m)
        #pragma unroll
        for (int n = 0; n < 2; ++n) { acc1[m][n] = (f32x4){0.f,0.f,0.f,0.f}; acc3[m][n] = (f32x4){0.f,0.f,0.f,0.f}; }

    s16x8 br1[2][2][2], br3[2][2][2];

    #pragma unroll
    for (int q = 0; q < 4; ++q) { cp16(pA[q], sA + (q * 4 + wid) * 1024); pA[q] += 128; }
    #pragma unroll
    for (int n = 0; n < 2; ++n)
        #pragma unroll
        for (int ks = 0; ks < 2; ++ks) {
            br1[0][n][ks] = *(const s16x8*)(pB1[n] + ks * 1024);
            br3[0][n][ks] = *(const s16x8*)(pB3[n] + ks * 1024);
        }
    #pragma unroll
    for (int n = 0; n < 2; ++n)
        #pragma unroll
        for (int ks = 0; ks < 2; ++ks) {
            br1[1][n][ks] = *(const s16x8*)(pB1[n] + (2 + ks) * 1024);
            br3[1][n][ks] = *(const s16x8*)(pB3[n] + (2 + ks) * 1024);
        }

    for (int tt = 0; tt < 7; ++tt) {
        #pragma unroll
        for (int half = 0; half < 2; ++half) {
            #pragma unroll
            for (int q = 0; q < 4; ++q) {
                cp16(pA[q], sA + (half ^ 1) * 16384 + (q * 4 + wid) * 1024);
                pA[q] += 128;
            }
            asm volatile("s_waitcnt vmcnt(12)" ::: "memory");
            __builtin_amdgcn_sched_barrier(0);
            __builtin_amdgcn_s_barrier();
            __builtin_amdgcn_sched_barrier(0);

            #pragma unroll
            for (int ks = 0; ks < 2; ++ks) {
                s16x8 a[4];
                #pragma unroll
                for (int m = 0; m < 4; ++m)
                    a[m] = *(const s16x8*)(sA + half * 16384 + m * 2048 + loA[ks]);
                #pragma unroll
                for (int n = 0; n < 2; ++n) {
                    #pragma unroll
                    for (int m = 0; m < 4; ++m) {
                        acc1[m][n] = __builtin_amdgcn_mfma_f32_16x16x32_bf16(a[m], br1[half][n][ks], acc1[m][n], 0, 0, 0);
                        acc3[m][n] = __builtin_amdgcn_mfma_f32_16x16x32_bf16(a[m], br3[half][n][ks], acc3[m][n], 0, 0, 0);
                    }
                }
            }
            #pragma unroll
            for (int n = 0; n < 2; ++n)
                #pragma unroll
                for (int ks = 0; ks < 2; ++ks) {
                    br1[half][n][ks] = *(const s16x8*)(pB1[n] + (half * 2 + 4 + ks) * 1024);
                    br3[half][n][ks] = *(const s16x8*)(pB3[n] + (half * 2 + 4 + ks) * 1024);
                }
            __builtin_amdgcn_sched_barrier(0);
            __builtin_amdgcn_s_barrier();
            __builtin_amdgcn_sched_barrier(0);
        }
        #pragma unroll
        for (int n = 0; n < 2; ++n) { pB1[n] += 4096; pB3[n] += 4096; }
    }
    // t=14
    #pragma unroll
    for (int q = 0; q < 4; ++q) cp16(pA[q], sA + 16384 + (q * 4 + wid) * 1024);
    asm volatile("s_waitcnt vmcnt(12)" ::: "memory");
    __builtin_amdgcn_sched_barrier(0);
    __builtin_amdgcn_s_barrier();
    __builtin_amdgcn_sched_barrier(0);
    #pragma unroll
    for (int ks = 0; ks < 2; ++ks) {
        s16x8 a[4];
        #pragma unroll
        for (int m = 0; m < 4; ++m)
            a[m] = *(const s16x8*)(sA + m * 2048 + loA[ks]);
        #pragma unroll
        for (int n = 0; n < 2; ++n)
            #pragma unroll
            for (int m = 0; m < 4; ++m) {
                acc1[m][n] = __builtin_amdgcn_mfma_f32_16x16x32_bf16(a[m], br1[0][n][ks], acc1[m][n], 0, 0, 0);
                acc3[m][n] = __builtin_amdgcn_mfma_f32_16x16x32_bf16(a[m], br3[0][n][ks], acc3[m][n], 0, 0, 0);
            }
    }
    __builtin_amdgcn_sched_barrier(0);
    __builtin_amdgcn_s_barrier();
    __builtin_amdgcn_sched_barrier(0);
    // t=15
    asm volatile("s_waitcnt vmcnt(0)" ::: "memory");
    __builtin_amdgcn_sched_barrier(0);
    __builtin_amdgcn_s_barrier();
    __builtin_amdgcn_sched_barrier(0);
    #pragma unroll
    for (int ks = 0; ks < 2; ++ks) {
        s16x8 a[4];
        #pragma unroll
        for (int m = 0; m < 4; ++m)
            a[m] = *(const s16x8*)(sA + 16384 + m * 2048 + loA[ks]);
        #pragma unroll
        for (int n = 0; n < 2; ++n)
            #pragma unroll
            for (int m = 0; m < 4; ++m) {
                acc1[m][n] = __builtin_amdgcn_mfma_f32_16x16x32_bf16(a[m], br1[1][n][ks], acc1[m][n], 0, 0, 0);
                acc3[m][n] = __builtin_amdgcn_mfma_f32_16x16x32_bf16(a[m], br3[1][n][ks], acc3[m][n], 0, 0, 0);
            }
    }

    #pragma unroll
    for (int m = 0; m < 4; ++m) {
        int rbase = wr * 64 + m * 16 + (lane >> 4) * 4;
        #pragma unroll
        for (int r = 0; r < 4; ++r) {
            int row = rbase + r;
            if (row < rm) {
                int hrow = rowSlot[row];
                #pragma unroll
                for (int n = 0; n < 2; ++n) {
                    float v1 = acc1[m][n][r], v3 = acc3[m][n][r];
                    float hv = (v1 / (1.0f + __expf(-v1))) * v3;
                    int col = n0 + wc * 32 + n * 16 + (lane & 15);
                    hbuf[(size_t)hrow * INTER + col] = f2bf(hv);
                }
            }
        }
    }
}

// ---------------- GEMM2: 1-D compact grid; obuf[slot] = h W2 ----------------
__global__ __launch_bounds__(256) void kgemm2(
    const unsigned short* __restrict__ hbuf,
    const unsigned short* __restrict__ w2t, const unsigned short* __restrict__ sw2t,
    const int* __restrict__ cnt, const int* __restrict__ ttab, const int* __restrict__ slots,
    unsigned short* __restrict__ obuf)
{
    int g = blockIdx.x;
    int tile = g >> 4;
    if (tile >= cnt[17]) return;
    int info = ttab[tile];
    int e = info >> 16;
    int m0 = info & 0xffff;
    int n0 = (g & 15) * 64;
    int n_rows, lbase;
    if (e < 8) { n_rows = cnt[e]; lbase = cnt[8 + e]; } else { n_rows = NT; lbase = 0; }
    int rm = min(128, n_rows - m0);
    const unsigned short* bp = (e < 8) ? (w2t + (size_t)e * DIM * INTER) : sw2t;

    __shared__ __align__(16) char sA[2][16384];
    __shared__ int rowH[128];

    int tid = threadIdx.x;
    if (tid < 128) {
        int r = m0 + min(tid, rm - 1);
        rowH[tid] = (e < 8) ? slots[lbase + r] : (4096 + r);
    }
    __syncthreads();

    int wid = tid >> 6, lane = tid & 63;
    int wr = wid >> 1, wc = wid & 1;
    int swz_st = (((lane & 7) ^ (lane >> 3)) - (lane & 7)) * 16;

    const char* pA[4];
    #pragma unroll
    for (int q = 0; q < 4; ++q) {
        int row = (q * 4 + wid) * 8 + (lane >> 3);
        pA[q] = (const char*)(hbuf + (size_t)rowH[row] * INTER) + (lane & 7) * 16 + swz_st;
    }
    const char* pB[2];
    #pragma unroll
    for (int n = 0; n < 2; ++n) {
        int nt = (n0 >> 4) + wc * 2 + n;
        pB[n] = (const char*)bp + (size_t)nt * 32768 + lane * 16;
    }

    int loA[2];
    #pragma unroll
    for (int ks = 0; ks < 2; ++ks) {
        int ch = ((ks * 4) + (lane >> 4)) ^ (lane & 7);
        loA[ks] = (wr * 64 + (lane & 15)) * 128 + ch * 16;
    }

    f32x4 acc[4][2];
    #pragma unroll
    for (int m = 0; m < 4; ++m)
        #pragma unroll
        for (int n = 0; n < 2; ++n) acc[m][n] = (f32x4){0.f,0.f,0.f,0.f};

    s16x8 br[2][2][2];

    #pragma unroll
    for (int q = 0; q < 4; ++q) { cp16(pA[q], (char*)sA + (q * 4 + wid) * 1024); pA[q] += 128; }
    #pragma unroll
    for (int n = 0; n < 2; ++n)
        #pragma unroll
        for (int ks = 0; ks < 2; ++ks)
            br[0][n][ks] = *(const s16x8*)(pB[n] + ks * 1024);
    #pragma unroll
    for (int n = 0; n < 2; ++n)
        #pragma unroll
        for (int ks = 0; ks < 2; ++ks)
            br[1][n][ks] = *(const s16x8*)(pB[n] + (2 + ks) * 1024);

    for (int tt = 0; tt < 7; ++tt) {
        #pragma unroll
        for (int half = 0; half < 2; ++half) {
            #pragma unroll
            for (int q = 0; q < 4; ++q) {
                cp16(pA[q], (char*)sA + (half ^ 1) * 16384 + (q * 4 + wid) * 1024);
                pA[q] += 128;
            }
            asm volatile("s_waitcnt vmcnt(8)" ::: "memory");
            __builtin_amdgcn_sched_barrier(0);
            __builtin_amdgcn_s_barrier();
            __builtin_amdgcn_sched_barrier(0);

            #pragma unroll
            for (int ks = 0; ks < 2; ++ks) {
                s16x8 a[4];
                #pragma unroll
                for (int m = 0; m < 4; ++m)
                    a[m] = *(const s16x8*)((const char*)sA + half * 16384 + m * 2048 + loA[ks]);
                #pragma unroll
                for (int n = 0; n < 2; ++n)
                    #pragma unroll
                    for (int m = 0; m < 4; ++m)
                        acc[m][n] = __builtin_amdgcn_mfma_f32_16x16x32_bf16(a[m], br[half][n][ks], acc[m][n], 0, 0, 0);
            }
            #pragma unroll
            for (int n = 0; n < 2; ++n)
                #pragma unroll
                for (int ks = 0; ks < 2; ++ks)
                    br[half][n][ks] = *(const s16x8*)(pB[n] + (half * 2 + 4 + ks) * 1024);
            __builtin_amdgcn_sched_barrier(0);
            __builtin_amdgcn_s_barrier();
            __builtin_amdgcn_sched_barrier(0);
        }
        #pragma unroll
        for (int n = 0; n < 2; ++n) pB[n] += 4096;
    }
    // t=14
    #pragma unroll
    for (int q = 0; q < 4; ++q) cp16(pA[q], (char*)sA + 16384 + (q * 4 + wid) * 1024);
    asm volatile("s_waitcnt vmcnt(8)" ::: "memory");
    __builtin_amdgcn_sched_barrier(0);
    __builtin_amdgcn_s_barrier();
    __builtin_amdgcn_sched_barrier(0);
    #pragma unroll
    for (int ks = 0; ks < 2; ++ks) {
        s16x8 a[4];
        #pragma unroll
        for (int m = 0; m < 4; ++m)
            a[m] = *(const s16x8*)((const char*)sA + m * 2048 + loA[ks]);
        #pragma unroll
        for (int n = 0; n < 2; ++n)
            #pragma unroll
            for (int m = 0; m < 4; ++m)
                acc[m][n] = __builtin_amdgcn_mfma_f32_16x16x32_bf16(a[m], br[0][n][ks], acc[m][n], 0, 0, 0);
    }
    __builtin_amdgcn_sched_barrier(0);
    __builtin_amdgcn_s_barrier();
    __builtin_amdgcn_sched_barrier(0);
    // t=15
    asm volatile("s_waitcnt vmcnt(0)" ::: "memory");
    __builtin_amdgcn_sched_barrier(0);
    __builtin_amdgcn_s_barrier();
    __builtin_amdgcn_sched_barrier(0);
    #pragma unroll
    for (int ks = 0; ks < 2; ++ks) {
        s16x8 a[4];
        #pragma unroll
        for (int m = 0; m < 4; ++m)
            a[m] = *(const s16x8*)((const char*)sA + 16384 + m * 2048 + loA[ks]);
        #pragma unroll
        for (int n = 0; n < 2; ++n)
            #pragma unroll
            for (int m = 0; m < 4; ++m)
                acc[m][n] = __builtin_amdgcn_mfma_f32_16x16x32_bf16(a[m], br[1][n][ks], acc[m][n], 0, 0, 0);
    }

    #pragma unroll
    for (int m = 0; m < 4; ++m) {
        int rbase = wr * 64 + m * 16 + (lane >> 4) * 4;
        #pragma unroll
        for (int r = 0; r < 4; ++r) {
            int row = rbase + r;
            if (row < rm) {
                int orow = rowH[row];
                #pragma unroll
                for (int n = 0; n < 2; ++n) {
                    int col = n0 + wc * 32 + n * 16 + (lane & 15);
                    obuf[(size_t)orow * DIM + col] = f2bf(acc[m][n][r]);
                }
            }
        }
    }
}

// ---------------- combine ----------------
__global__ __launch_bounds__(256) void kcombine(const unsigned short* __restrict__ obuf,
                                                const float2* __restrict__ wts2,
                                                float* __restrict__ out)
{
    int gid = blockIdx.x * 256 + threadIdx.x;
    int t = gid >> 7;
    int d0 = (gid & 127) * 8;
    float2 w = wts2[t];
    u16x8 r0 = *(const u16x8*)&obuf[(size_t)(2 * t)     * DIM + d0];
    u16x8 r1 = *(const u16x8*)&obuf[(size_t)(2 * t + 1) * DIM + d0];
    u16x8 rs = *(const u16x8*)&obuf[(size_t)(4096 + t)  * DIM + d0];
    f32x4 o0, o1;
    #pragma unroll
    for (int j = 0; j < 4; ++j) o0[j] = w.x * bf2f(r0[j]) + w.y * bf2f(r1[j]) + bf2f(rs[j]);
    #pragma unroll
    for (int j = 0; j < 4; ++j) o1[j] = w.x * bf2f(r0[4+j]) + w.y * bf2f(r1[4+j]) + bf2f(rs[4+j]);
    f32x4* dst = (f32x4*)&out[(size_t)t * DIM + d0];
    dst[0] = o0; dst[1] = o1;
}

extern "C" void kernel_launch(void* const* d_in, const int* in_sizes, int n_in,
                              void* d_out, int out_size, void* d_ws, size_t ws_size,
                              hipStream_t stream) {
    const float* x      = (const float*)d_in[0];
    const float* gate_w = (const float*)d_in[1];
    const float* w1     = (const float*)d_in[2];
    const float* w2     = (const float*)d_in[3];
    const float* w3     = (const float*)d_in[4];
    const float* sw1    = (const float*)d_in[5];
    const float* sw2    = (const float*)d_in[6];
    const float* sw3    = (const float*)d_in[7];
    float* out = (float*)d_out;

    if (ws_size < (size_t)WS_NEED) return;

    char* ws = (char*)d_ws;
    int*            cnt      = (int*)(ws + WS_CNT);
    int*            slots    = (int*)(ws + WS_SLOT);
    int*            ttab     = (int*)(ws + WS_TTAB);
    int*            assign   = (int*)(ws + WS_ASSIGN);
    float*          wts      = (float*)(ws + WS_WT);
    float2*         wts2     = (float2*)(ws + WS_WTS2);
    unsigned short* xb       = (unsigned short*)(ws + WS_XB);
    unsigned short* hbuf     = (unsigned short*)(ws + WS_H);
    unsigned short* w1t      = (unsigned short*)(ws + WS_W1T);
    unsigned short* w3t      = (unsigned short*)(ws + WS_W3T);
    unsigned short* w2t      = (unsigned short*)(ws + WS_W2T);
    unsigned short* sw1t     = (unsigned short*)(ws + WS_SW1T);
    unsigned short* sw3t     = (unsigned short*)(ws + WS_SW3T);
    unsigned short* sw2t     = (unsigned short*)(ws + WS_SW2T);
    unsigned short* obuf     = (unsigned short*)(ws + WS_OBUF);

    kfat1<<<dim3(2816), 256, 0, stream>>>(x, gate_w, w1, w3, sw1, sw3,
                                          w1t, w3t, sw1t, sw3t, assign, wts2, xb);
    kscatter<<<dim3(1), 256, 0, stream>>>(assign, wts2, cnt, ttab, slots, wts);
    kfat2<<<dim3(1152 + 56 * 16), 256, 0, stream>>>(xb, w1t, w3t, sw1t, sw3t, cnt, ttab, slots, hbuf,
                                                    w2, sw2, w2t, sw2t);
    kgemm2<<<dim3(56 * 16), 256, 0, stream>>>(hbuf, w2t, sw2t, cnt, ttab, slots, obuf);
    kcombine<<<dim3(1024), 256, 0, stream>>>(obuf, wts2, out);
}

// Round 18
// 128.011 us; speedup vs baseline: 1.0368x; 1.0368x over previous
//
#include <hip/hip_runtime.h>
#include <hip/hip_bf16.h>
#include <cstdint>
#include <cstddef>

#define DIM   1024
#define INTER 1024
#define NT    2048      // tokens

typedef __attribute__((ext_vector_type(4))) float  f32x4;
typedef __attribute__((ext_vector_type(8))) short  s16x8;
typedef __attribute__((ext_vector_type(8))) unsigned short u16x8;

// workspace layout (bytes)
#define WS_CNT    0u
#define WS_SLOT   256u
#define WS_ASSIGN 33024u
#define WS_WT     65792u
#define WS_WTS2   98560u
#define WS_XB     131584u     // [2048][1024] bf16
#define WS_H      4325888u    // [6144][1024] bf16
#define WS_W1T    16908800u   // frag-linear bf16 weights; obuf after kfat2
#define WS_W3T    33686016u
#define WS_W2T    50463232u
#define WS_SW1T   67240448u
#define WS_SW3T   69337600u
#define WS_SW2T   71434752u
#define WS_NEED   73531904u
#define WS_OBUF   WS_W1T

__device__ __forceinline__ unsigned short f2bf(float f) {
    unsigned int u = __float_as_uint(f);
    return (unsigned short)((u + 0x7fffu + ((u >> 16) & 1u)) >> 16);
}
__device__ __forceinline__ float bf2f(unsigned short v) {
    return __uint_as_float(((unsigned int)v) << 16);
}

__device__ __forceinline__ void cp16(const void* g, void* l) {
    __builtin_amdgcn_global_load_lds((const __attribute__((address_space(1))) void*)g,
                                     (__attribute__((address_space(3))) void*)l, 16, 0, 0);
}

// ---------------- fat1: conv(w1,w3,sw1,sw3) [blocks 0..2303] + gate [2304..2815] ----------------
// Conv phase-2 LDS column reads were 4-way bank-conflicted; fixed via
// both-sides XOR: phase-1 pre-swizzles the GLOBAL source byte-64 chunk by
// (w&1)<<6 (wave-uniform, == (row>>4)&1), phase-2 XORs the column by
// ((l>>5)&1)<<4 (== (row>>4)&1 for its rows). Windows split across both
// 16-bank halves -> 2-way = free.
__global__ __launch_bounds__(256) void kfat1(
    const float* __restrict__ x, const float* __restrict__ gw,
    const float* __restrict__ w1, const float* __restrict__ w3,
    const float* __restrict__ sw1, const float* __restrict__ sw3,
    unsigned short* __restrict__ w1t, unsigned short* __restrict__ w3t,
    unsigned short* __restrict__ sw1t, unsigned short* __restrict__ sw3t,
    int* __restrict__ assign, float2* __restrict__ wts2, unsigned short* __restrict__ xb)
{
    __shared__ __align__(16) char smem[32768];
    int bid = blockIdx.x;
    int tid = threadIdx.x;
    if (bid < 2304) {
        int slab = bid >> 7, t = bid & 127;
        int r0 = (t >> 3) * 64, c0 = (t & 7) * 128;
        const float* src; unsigned short* dst;
        if (slab < 8)        { src = w1 + (size_t)slab * DIM * INTER;       dst = w1t + (size_t)slab * DIM * INTER; }
        else if (slab < 16)  { src = w3 + (size_t)(slab - 8) * DIM * INTER; dst = w3t + (size_t)(slab - 8) * DIM * INTER; }
        else if (slab == 16) { src = sw1; dst = sw1t; }
        else                 { src = sw3; dst = sw3t; }

        int w = tid >> 6, l = tid & 63;
        size_t lanoff = (size_t)(l >> 5) * 4096 + (size_t)((((l & 31) * 16)) ^ ((w & 1) << 6));
        const char* gbase = (const char*)src + (size_t)r0 * 4096 + (size_t)c0 * 4;
        #pragma unroll
        for (int i = 0; i < 8; ++i)
            cp16(gbase + (size_t)(w * 16 + i * 2) * 4096 + lanoff, smem + (w * 16 + i * 2) * 512);
        asm volatile("s_waitcnt vmcnt(0)" ::: "memory");
        __builtin_amdgcn_sched_barrier(0);
        __builtin_amdgcn_s_barrier();
        __builtin_amdgcn_sched_barrier(0);
        const float* ldsf = (const float*)smem;
        int cl = l & 15, kg = l >> 4;
        int csw = (((l >> 5) & 1) << 4);
        #pragma unroll
        for (int i = 0; i < 4; ++i) {
            int f = w * 4 + i;             // 0..15 = 8 nt x 2 kt
            int ntl = f >> 1, ktl = f & 1;
            u16x8 o;
            #pragma unroll
            for (int j = 0; j < 8; ++j)
                o[j] = f2bf(ldsf[(ktl * 32 + kg * 8 + j) * 128 + ((ntl * 16 + cl) ^ csw)]);
            size_t off = ((size_t)((c0 >> 4) + ntl) * 32 + (r0 >> 5) + ktl) * 512 + l * 8;
            *(u16x8*)(dst + off) = o;
        }
        return;
    }
    // ---- gate ----
    int wid = tid >> 6, lane = tid & 63;
    int t = (bid - 2304) * 4 + wid;
    const float* xrow = x + (size_t)t * DIM;

    float xr[16];
    float acc[8] = {0.f,0.f,0.f,0.f,0.f,0.f,0.f,0.f};
    #pragma unroll
    for (int j = 0; j < 16; ++j) {
        float xv = xrow[j * 64 + lane];
        xr[j] = xv;
        const f32x4* g = (const f32x4*)(gw + (size_t)(j * 64 + lane) * 8);
        f32x4 g0 = g[0], g1 = g[1];
        acc[0] += xv * g0[0]; acc[1] += xv * g0[1]; acc[2] += xv * g0[2]; acc[3] += xv * g0[3];
        acc[4] += xv * g1[0]; acc[5] += xv * g1[1]; acc[6] += xv * g1[2]; acc[7] += xv * g1[3];
    }
    #pragma unroll
    for (int j = 0; j < 16; ++j) xb[(size_t)t * DIM + j * 64 + lane] = f2bf(xr[j]);

    #pragma unroll
    for (int e = 0; e < 8; ++e) {
        float v = acc[e];
        v += __shfl_xor(v, 1);  v += __shfl_xor(v, 2);  v += __shfl_xor(v, 4);
        v += __shfl_xor(v, 8);  v += __shfl_xor(v, 16); v += __shfl_xor(v, 32);
        acc[e] = v;
    }
    float mx = acc[0];
    #pragma unroll
    for (int e = 1; e < 8; ++e) mx = fmaxf(mx, acc[e]);
    float p[8]; float se = 0.f;
    #pragma unroll
    for (int e = 0; e < 8; ++e) { p[e] = expf(acc[e] - mx); se += p[e]; }
    float inv = 1.0f / se;
    int i0 = 0; float b0 = p[0];
    #pragma unroll
    for (int e = 1; e < 8; ++e) if (p[e] > b0) { b0 = p[e]; i0 = e; }
    int i1 = -1; float b1 = -1.f;
    #pragma unroll
    for (int e = 0; e < 8; ++e) if (e != i0 && p[e] > b1) { b1 = p[e]; i1 = e; }
    if (lane == 0) {
        assign[t] = i0 | (i1 << 8);
        wts2[t] = make_float2(b0 * inv, b1 * inv);
    }
}

// ---------------- scatter ----------------
__global__ __launch_bounds__(256) void kscatter(const int* __restrict__ assign,
                                                const float2* __restrict__ wts2,
                                                int* __restrict__ cnt,
                                                int* __restrict__ slots,
                                                float* __restrict__ wts)
{
    __shared__ int h[8], pos[8];
    int tid = threadIdx.x, lane = tid & 63;
    if (tid < 8) h[tid] = 0;
    __syncthreads();

    for (int base = 0; base < NT; base += 256) {
        int a = assign[base + tid];
        int e0 = a & 255, e1 = (a >> 8) & 255;
        #pragma unroll
        for (int e = 0; e < 8; ++e) {
            unsigned long long m0 = __ballot(e0 == e);
            unsigned long long m1 = __ballot(e1 == e);
            if (lane == 0) {
                int c = __popcll(m0) + __popcll(m1);
                if (c) atomicAdd(&h[e], c);
            }
        }
    }
    __syncthreads();
    if (tid == 0) {
        int run = 0;
        #pragma unroll
        for (int e = 0; e < 8; ++e) {
            cnt[8 + e] = run; pos[e] = run;
            cnt[e] = h[e]; run += h[e];
        }
        cnt[16] = run;
    }
    __syncthreads();

    for (int base = 0; base < NT; base += 256) {
        int t = base + tid;
        int a = assign[t];
        float2 w = wts2[t];
        int e0 = a & 255, e1 = (a >> 8) & 255;
        unsigned long long lt = (1ull << lane) - 1ull;
        #pragma unroll
        for (int e = 0; e < 8; ++e) {
            unsigned long long m0 = __ballot(e0 == e);
            unsigned long long m1 = __ballot(e1 == e);
            int c = __popcll(m0) + __popcll(m1);
            int b = 0;
            if (lane == 0 && c) b = atomicAdd(&pos[e], c);
            b = __shfl(b, 0);
            if (e0 == e) { int r = __popcll(m0 & lt);                 slots[b + r] = t * 2;     wts[b + r] = w.x; }
            if (e1 == e) { int r = __popcll(m0) + __popcll(m1 & lt);  slots[b + r] = t * 2 + 1; wts[b + r] = w.y; }
        }
    }
}

// ---------------- fat2: GEMM1 (z<9) + conv(w2,sw2) (z>=9, x<8) ----------------
// GEMM1: BM=128 BN=64 BK=64; 4 waves 2x2. A LDS dbuf (cp16+swizzle); B depth-2
// register prefetch from frag-linear weights.
__global__ __launch_bounds__(256) void kfat2(
    const unsigned short* __restrict__ xb,
    const unsigned short* __restrict__ w1t, const unsigned short* __restrict__ w3t,
    const unsigned short* __restrict__ sw1t, const unsigned short* __restrict__ sw3t,
    const int* __restrict__ cnt, const int* __restrict__ slots,
    unsigned short* __restrict__ hbuf,
    const float* __restrict__ w2, const float* __restrict__ sw2,
    unsigned short* __restrict__ w2t, unsigned short* __restrict__ sw2t)
{
    __shared__ __align__(16) char smem[34048];
    int z = blockIdx.z;
    int tid = threadIdx.x;
    if (z >= 9) {
        if (blockIdx.x >= 8) return;
        int slab = z - 9;
        const float* src; unsigned short* dst;
        if (slab < 8) { src = w2 + (size_t)slab * DIM * INTER; dst = w2t + (size_t)slab * DIM * INTER; }
        else          { src = sw2; dst = sw2t; }
        int r0 = blockIdx.y * 64, c0 = blockIdx.x * 128;

        int w = tid >> 6, l = tid & 63;
        size_t lanoff = (size_t)(l >> 5) * 4096 + (size_t)((((l & 31) * 16)) ^ ((w & 1) << 6));
        const char* gbase = (const char*)src + (size_t)r0 * 4096 + (size_t)c0 * 4;
        #pragma unroll
        for (int i = 0; i < 8; ++i)
            cp16(gbase + (size_t)(w * 16 + i * 2) * 4096 + lanoff, smem + (w * 16 + i * 2) * 512);
        asm volatile("s_waitcnt vmcnt(0)" ::: "memory");
        __builtin_amdgcn_sched_barrier(0);
        __builtin_amdgcn_s_barrier();
        __builtin_amdgcn_sched_barrier(0);
        const float* ldsf = (const float*)smem;
        int cl = l & 15, kg = l >> 4;
        int csw = (((l >> 5) & 1) << 4);
        #pragma unroll
        for (int i = 0; i < 4; ++i) {
            int f = w * 4 + i;
            int ntl = f >> 1, ktl = f & 1;
            u16x8 o;
            #pragma unroll
            for (int j = 0; j < 8; ++j)
                o[j] = f2bf(ldsf[(ktl * 32 + kg * 8 + j) * 128 + ((ntl * 16 + cl) ^ csw)]);
            size_t off = ((size_t)((c0 >> 4) + ntl) * 32 + (r0 >> 5) + ktl) * 512 + l * 8;
            *(u16x8*)(dst + off) = o;
        }
        return;
    }

    int e = z;
    int m0 = blockIdx.y * 128;
    int n0 = blockIdx.x * 64;
    int n_rows, lbase;
    if (e < 8) { n_rows = cnt[e]; lbase = cnt[8 + e]; } else { n_rows = NT; lbase = 0; }
    if (m0 >= n_rows) return;
    int rm = min(128, n_rows - m0);

    const unsigned short* b1p = (e < 8) ? (w1t + (size_t)e * DIM * INTER) : sw1t;
    const unsigned short* b3p = (e < 8) ? (w3t + (size_t)e * DIM * INTER) : sw3t;

    char* sA = smem;                       // [2][16384] A dbuf
    int* rowTok  = (int*)(smem + 32768);
    int* rowSlot = (int*)(smem + 33280);

    if (tid < 128) {
        int r = m0 + min(tid, rm - 1);
        int slot, tok;
        if (e < 8) { slot = slots[lbase + r]; tok = slot >> 1; }
        else       { tok = r; slot = 4096 + r; }
        rowTok[tid] = tok;
        rowSlot[tid] = slot;
    }
    __syncthreads();

    int wid = tid >> 6, lane = tid & 63;
    int wr = wid >> 1, wc = wid & 1;
    int swz_st = (((lane & 7) ^ (lane >> 3)) - (lane & 7)) * 16;

    const char* pA[4];
    #pragma unroll
    for (int q = 0; q < 4; ++q) {
        int row = (q * 4 + wid) * 8 + (lane >> 3);
        pA[q] = (const char*)(xb + (size_t)rowTok[row] * DIM) + (lane & 7) * 16 + swz_st;
    }
    const char* pB1[2]; const char* pB3[2];
    #pragma unroll
    for (int n = 0; n < 2; ++n) {
        int nt = (n0 >> 4) + wc * 2 + n;
        pB1[n] = (const char*)b1p + (size_t)nt * 32768 + lane * 16;
        pB3[n] = (const char*)b3p + (size_t)nt * 32768 + lane * 16;
    }

    int loA[2];
    #pragma unroll
    for (int ks = 0; ks < 2; ++ks) {
        int ch = ((ks * 4) + (lane >> 4)) ^ (lane & 7);
        loA[ks] = (wr * 64 + (lane & 15)) * 128 + ch * 16;
    }

    f32x4 acc1[4][2], acc3[4][2];
    #pragma unroll
    for (int m = 0; m < 4; ++m)
        #pragma unroll
        for (int n = 0; n < 2; ++n) { acc1[m][n] = (f32x4){0.f,0.f,0.f,0.f}; acc3[m][n] = (f32x4){0.f,0.f,0.f,0.f}; }

    s16x8 br1[2][2][2], br3[2][2][2];   // [slot][n][ks]

    // prologue: A0 -> sA[0]; B0 -> br[0]; B1 -> br[1]
    #pragma unroll
    for (int q = 0; q < 4; ++q) { cp16(pA[q], sA + (q * 4 + wid) * 1024); pA[q] += 128; }
    #pragma unroll
    for (int n = 0; n < 2; ++n)
        #pragma unroll
        for (int ks = 0; ks < 2; ++ks) {
            br1[0][n][ks] = *(const s16x8*)(pB1[n] + ks * 1024);
            br3[0][n][ks] = *(const s16x8*)(pB3[n] + ks * 1024);
        }
    #pragma unroll
    for (int n = 0; n < 2; ++n)
        #pragma unroll
        for (int ks = 0; ks < 2; ++ks) {
            br1[1][n][ks] = *(const s16x8*)(pB1[n] + (2 + ks) * 1024);
            br3[1][n][ks] = *(const s16x8*)(pB3[n] + (2 + ks) * 1024);
        }

    for (int tt = 0; tt < 7; ++tt) {
        #pragma unroll
        for (int half = 0; half < 2; ++half) {
            #pragma unroll
            for (int q = 0; q < 4; ++q) {
                cp16(pA[q], sA + (half ^ 1) * 16384 + (q * 4 + wid) * 1024);
                pA[q] += 128;
            }
            asm volatile("s_waitcnt vmcnt(12)" ::: "memory");
            __builtin_amdgcn_sched_barrier(0);
            __builtin_amdgcn_s_barrier();
            __builtin_amdgcn_sched_barrier(0);

            #pragma unroll
            for (int ks = 0; ks < 2; ++ks) {
                s16x8 a[4];
                #pragma unroll
                for (int m = 0; m < 4; ++m)
                    a[m] = *(const s16x8*)(sA + half * 16384 + m * 2048 + loA[ks]);
                #pragma unroll
                for (int n = 0; n < 2; ++n) {
                    #pragma unroll
                    for (int m = 0; m < 4; ++m) {
                        acc1[m][n] = __builtin_amdgcn_mfma_f32_16x16x32_bf16(a[m], br1[half][n][ks], acc1[m][n], 0, 0, 0);
                        acc3[m][n] = __builtin_amdgcn_mfma_f32_16x16x32_bf16(a[m], br3[half][n][ks], acc3[m][n], 0, 0, 0);
                    }
                }
            }
            #pragma unroll
            for (int n = 0; n < 2; ++n)
                #pragma unroll
                for (int ks = 0; ks < 2; ++ks) {
                    br1[half][n][ks] = *(const s16x8*)(pB1[n] + (half * 2 + 4 + ks) * 1024);
                    br3[half][n][ks] = *(const s16x8*)(pB3[n] + (half * 2 + 4 + ks) * 1024);
                }
            __builtin_amdgcn_sched_barrier(0);
            __builtin_amdgcn_s_barrier();
            __builtin_amdgcn_sched_barrier(0);
        }
        #pragma unroll
        for (int n = 0; n < 2; ++n) { pB1[n] += 4096; pB3[n] += 4096; }
    }
    // t=14
    #pragma unroll
    for (int q = 0; q < 4; ++q) cp16(pA[q], sA + 16384 + (q * 4 + wid) * 1024);
    asm volatile("s_waitcnt vmcnt(12)" ::: "memory");
    __builtin_amdgcn_sched_barrier(0);
    __builtin_amdgcn_s_barrier();
    __builtin_amdgcn_sched_barrier(0);
    #pragma unroll
    for (int ks = 0; ks < 2; ++ks) {
        s16x8 a[4];
        #pragma unroll
        for (int m = 0; m < 4; ++m)
            a[m] = *(const s16x8*)(sA + m * 2048 + loA[ks]);
        #pragma unroll
        for (int n = 0; n < 2; ++n)
            #pragma unroll
            for (int m = 0; m < 4; ++m) {
                acc1[m][n] = __builtin_amdgcn_mfma_f32_16x16x32_bf16(a[m], br1[0][n][ks], acc1[m][n], 0, 0, 0);
                acc3[m][n] = __builtin_amdgcn_mfma_f32_16x16x32_bf16(a[m], br3[0][n][ks], acc3[m][n], 0, 0, 0);
            }
    }
    __builtin_amdgcn_sched_barrier(0);
    __builtin_amdgcn_s_barrier();
    __builtin_amdgcn_sched_barrier(0);
    // t=15
    asm volatile("s_waitcnt vmcnt(0)" ::: "memory");
    __builtin_amdgcn_sched_barrier(0);
    __builtin_amdgcn_s_barrier();
    __builtin_amdgcn_sched_barrier(0);
    #pragma unroll
    for (int ks = 0; ks < 2; ++ks) {
        s16x8 a[4];
        #pragma unroll
        for (int m = 0; m < 4; ++m)
            a[m] = *(const s16x8*)(sA + 16384 + m * 2048 + loA[ks]);
        #pragma unroll
        for (int n = 0; n < 2; ++n)
            #pragma unroll
            for (int m = 0; m < 4; ++m) {
                acc1[m][n] = __builtin_amdgcn_mfma_f32_16x16x32_bf16(a[m], br1[1][n][ks], acc1[m][n], 0, 0, 0);
                acc3[m][n] = __builtin_amdgcn_mfma_f32_16x16x32_bf16(a[m], br3[1][n][ks], acc3[m][n], 0, 0, 0);
            }
    }

    #pragma unroll
    for (int m = 0; m < 4; ++m) {
        int rbase = wr * 64 + m * 16 + (lane >> 4) * 4;
        #pragma unroll
        for (int r = 0; r < 4; ++r) {
            int row = rbase + r;
            if (row < rm) {
                int hrow = rowSlot[row];
                #pragma unroll
                for (int n = 0; n < 2; ++n) {
                    float v1 = acc1[m][n][r], v3 = acc3[m][n][r];
                    float hv = (v1 / (1.0f + __expf(-v1))) * v3;
                    int col = n0 + wc * 32 + n * 16 + (lane & 15);
                    hbuf[(size_t)hrow * INTER + col] = f2bf(hv);
                }
            }
        }
    }
}

// ---------------- GEMM2: obuf[slot] = h W2 (A LDS dbuf; B depth-2 reg prefetch) ----------------
__global__ __launch_bounds__(256) void kgemm2(
    const unsigned short* __restrict__ hbuf,
    const unsigned short* __restrict__ w2t, const unsigned short* __restrict__ sw2t,
    const int* __restrict__ cnt, const int* __restrict__ slots,
    unsigned short* __restrict__ obuf)
{
    int e = blockIdx.z;
    int m0 = blockIdx.y * 128;
    int n0 = blockIdx.x * 64;
    int n_rows, lbase;
    if (e < 8) { n_rows = cnt[e]; lbase = cnt[8 + e]; } else { n_rows = NT; lbase = 0; }
    if (m0 >= n_rows) return;
    int rm = min(128, n_rows - m0);
    const unsigned short* bp = (e < 8) ? (w2t + (size_t)e * DIM * INTER) : sw2t;

    __shared__ __align__(16) char sA[2][16384];
    __shared__ int rowH[128];

    int tid = threadIdx.x;
    if (tid < 128) {
        int r = m0 + min(tid, rm - 1);
        rowH[tid] = (e < 8) ? slots[lbase + r] : (4096 + r);
    }
    __syncthreads();

    int wid = tid >> 6, lane = tid & 63;
    int wr = wid >> 1, wc = wid & 1;
    int swz_st = (((lane & 7) ^ (lane >> 3)) - (lane & 7)) * 16;

    const char* pA[4];
    #pragma unroll
    for (int q = 0; q < 4; ++q) {
        int row = (q * 4 + wid) * 8 + (lane >> 3);
        pA[q] = (const char*)(hbuf + (size_t)rowH[row] * INTER) + (lane & 7) * 16 + swz_st;
    }
    const char* pB[2];
    #pragma unroll
    for (int n = 0; n < 2; ++n) {
        int nt = (n0 >> 4) + wc * 2 + n;
        pB[n] = (const char*)bp + (size_t)nt * 32768 + lane * 16;
    }

    int loA[2];
    #pragma unroll
    for (int ks = 0; ks < 2; ++ks) {
        int ch = ((ks * 4) + (lane >> 4)) ^ (lane & 7);
        loA[ks] = (wr * 64 + (lane & 15)) * 128 + ch * 16;
    }

    f32x4 acc[4][2];
    #pragma unroll
    for (int m = 0; m < 4; ++m)
        #pragma unroll
        for (int n = 0; n < 2; ++n) acc[m][n] = (f32x4){0.f,0.f,0.f,0.f};

    s16x8 br[2][2][2];

    #pragma unroll
    for (int q = 0; q < 4; ++q) { cp16(pA[q], (char*)sA + (q * 4 + wid) * 1024); pA[q] += 128; }
    #pragma unroll
    for (int n = 0; n < 2; ++n)
        #pragma unroll
        for (int ks = 0; ks < 2; ++ks)
            br[0][n][ks] = *(const s16x8*)(pB[n] + ks * 1024);
    #pragma unroll
    for (int n = 0; n < 2; ++n)
        #pragma unroll
        for (int ks = 0; ks < 2; ++ks)
            br[1][n][ks] = *(const s16x8*)(pB[n] + (2 + ks) * 1024);

    for (int tt = 0; tt < 7; ++tt) {
        #pragma unroll
        for (int half = 0; half < 2; ++half) {
            #pragma unroll
            for (int q = 0; q < 4; ++q) {
                cp16(pA[q], (char*)sA + (half ^ 1) * 16384 + (q * 4 + wid) * 1024);
                pA[q] += 128;
            }
            asm volatile("s_waitcnt vmcnt(8)" ::: "memory");
            __builtin_amdgcn_sched_barrier(0);
            __builtin_amdgcn_s_barrier();
            __builtin_amdgcn_sched_barrier(0);

            #pragma unroll
            for (int ks = 0; ks < 2; ++ks) {
                s16x8 a[4];
                #pragma unroll
                for (int m = 0; m < 4; ++m)
                    a[m] = *(const s16x8*)((const char*)sA + half * 16384 + m * 2048 + loA[ks]);
                #pragma unroll
                for (int n = 0; n < 2; ++n)
                    #pragma unroll
                    for (int m = 0; m < 4; ++m)
                        acc[m][n] = __builtin_amdgcn_mfma_f32_16x16x32_bf16(a[m], br[half][n][ks], acc[m][n], 0, 0, 0);
            }
            #pragma unroll
            for (int n = 0; n < 2; ++n)
                #pragma unroll
                for (int ks = 0; ks < 2; ++ks)
                    br[half][n][ks] = *(const s16x8*)(pB[n] + (half * 2 + 4 + ks) * 1024);
            __builtin_amdgcn_sched_barrier(0);
            __builtin_amdgcn_s_barrier();
            __builtin_amdgcn_sched_barrier(0);
        }
        #pragma unroll
        for (int n = 0; n < 2; ++n) pB[n] += 4096;
    }
    // t=14
    #pragma unroll
    for (int q = 0; q < 4; ++q) cp16(pA[q], (char*)sA + 16384 + (q * 4 + wid) * 1024);
    asm volatile("s_waitcnt vmcnt(8)" ::: "memory");
    __builtin_amdgcn_sched_barrier(0);
    __builtin_amdgcn_s_barrier();
    __builtin_amdgcn_sched_barrier(0);
    #pragma unroll
    for (int ks = 0; ks < 2; ++ks) {
        s16x8 a[4];
        #pragma unroll
        for (int m = 0; m < 4; ++m)
            a[m] = *(const s16x8*)((const char*)sA + m * 2048 + loA[ks]);
        #pragma unroll
        for (int n = 0; n < 2; ++n)
            #pragma unroll
            for (int m = 0; m < 4; ++m)
                acc[m][n] = __builtin_amdgcn_mfma_f32_16x16x32_bf16(a[m], br[0][n][ks], acc[m][n], 0, 0, 0);
    }
    __builtin_amdgcn_sched_barrier(0);
    __builtin_amdgcn_s_barrier();
    __builtin_amdgcn_sched_barrier(0);
    // t=15
    asm volatile("s_waitcnt vmcnt(0)" ::: "memory");
    __builtin_amdgcn_sched_barrier(0);
    __builtin_amdgcn_s_barrier();
    __builtin_amdgcn_sched_barrier(0);
    #pragma unroll
    for (int ks = 0; ks < 2; ++ks) {
        s16x8 a[4];
        #pragma unroll
        for (int m = 0; m < 4; ++m)
            a[m] = *(const s16x8*)((const char*)sA + 16384 + m * 2048 + loA[ks]);
        #pragma unroll
        for (int n = 0; n < 2; ++n)
            #pragma unroll
            for (int m = 0; m < 4; ++m)
                acc[m][n] = __builtin_amdgcn_mfma_f32_16x16x32_bf16(a[m], br[1][n][ks], acc[m][n], 0, 0, 0);
    }

    #pragma unroll
    for (int m = 0; m < 4; ++m) {
        int rbase = wr * 64 + m * 16 + (lane >> 4) * 4;
        #pragma unroll
        for (int r = 0; r < 4; ++r) {
            int row = rbase + r;
            if (row < rm) {
                int orow = rowH[row];
                #pragma unroll
                for (int n = 0; n < 2; ++n) {
                    int col = n0 + wc * 32 + n * 16 + (lane & 15);
                    obuf[(size_t)orow * DIM + col] = f2bf(acc[m][n][r]);
                }
            }
        }
    }
}

// ---------------- combine ----------------
__global__ __launch_bounds__(256) void kcombine(const unsigned short* __restrict__ obuf,
                                                const float2* __restrict__ wts2,
                                                float* __restrict__ out)
{
    int gid = blockIdx.x * 256 + threadIdx.x;
    int t = gid >> 7;
    int d0 = (gid & 127) * 8;
    float2 w = wts2[t];
    u16x8 r0 = *(const u16x8*)&obuf[(size_t)(2 * t)     * DIM + d0];
    u16x8 r1 = *(const u16x8*)&obuf[(size_t)(2 * t + 1) * DIM + d0];
    u16x8 rs = *(const u16x8*)&obuf[(size_t)(4096 + t)  * DIM + d0];
    f32x4 o0, o1;
    #pragma unroll
    for (int j = 0; j < 4; ++j) o0[j] = w.x * bf2f(r0[j]) + w.y * bf2f(r1[j]) + bf2f(rs[j]);
    #pragma unroll
    for (int j = 0; j < 4; ++j) o1[j] = w.x * bf2f(r0[4+j]) + w.y * bf2f(r1[4+j]) + bf2f(rs[4+j]);
    f32x4* dst = (f32x4*)&out[(size_t)t * DIM + d0];
    dst[0] = o0; dst[1] = o1;
}

extern "C" void kernel_launch(void* const* d_in, const int* in_sizes, int n_in,
                              void* d_out, int out_size, void* d_ws, size_t ws_size,
                              hipStream_t stream) {
    const float* x      = (const float*)d_in[0];
    const float* gate_w = (const float*)d_in[1];
    const float* w1     = (const float*)d_in[2];
    const float* w2     = (const float*)d_in[3];
    const float* w3     = (const float*)d_in[4];
    const float* sw1    = (const float*)d_in[5];
    const float* sw2    = (const float*)d_in[6];
    const float* sw3    = (const float*)d_in[7];
    float* out = (float*)d_out;

    if (ws_size < (size_t)WS_NEED) return;

    char* ws = (char*)d_ws;
    int*            cnt      = (int*)(ws + WS_CNT);
    int*            slots    = (int*)(ws + WS_SLOT);
    int*            assign   = (int*)(ws + WS_ASSIGN);
    float*          wts      = (float*)(ws + WS_WT);
    float2*         wts2     = (float2*)(ws + WS_WTS2);
    unsigned short* xb       = (unsigned short*)(ws + WS_XB);
    unsigned short* hbuf     = (unsigned short*)(ws + WS_H);
    unsigned short* w1t      = (unsigned short*)(ws + WS_W1T);
    unsigned short* w3t      = (unsigned short*)(ws + WS_W3T);
    unsigned short* w2t      = (unsigned short*)(ws + WS_W2T);
    unsigned short* sw1t     = (unsigned short*)(ws + WS_SW1T);
    unsigned short* sw3t     = (unsigned short*)(ws + WS_SW3T);
    unsigned short* sw2t     = (unsigned short*)(ws + WS_SW2T);
    unsigned short* obuf     = (unsigned short*)(ws + WS_OBUF);

    kfat1<<<dim3(2816), 256, 0, stream>>>(x, gate_w, w1, w3, sw1, sw3,
                                          w1t, w3t, sw1t, sw3t, assign, wts2, xb);
    kscatter<<<dim3(1), 256, 0, stream>>>(assign, wts2, cnt, slots, wts);
    kfat2<<<dim3(16, 16, 18), 256, 0, stream>>>(xb, w1t, w3t, sw1t, sw3t, cnt, slots, hbuf,
                                                w2, sw2, w2t, sw2t);
    kgemm2<<<dim3(16, 16, 9), 256, 0, stream>>>(hbuf, w2t, sw2t, cnt, slots, obuf);
    kcombine<<<dim3(1024), 256, 0, stream>>>(obuf, wts2, out);
}

// Round 19
// 114.184 us; speedup vs baseline: 1.1624x; 1.1211x over previous
//
#include <hip/hip_runtime.h>
#include <hip/hip_bf16.h>
#include <cstdint>
#include <cstddef>

#define DIM   1024
#define INTER 1024
#define NT    2048      // tokens

typedef __attribute__((ext_vector_type(4))) float  f32x4;
typedef __attribute__((ext_vector_type(8))) short  s16x8;
typedef __attribute__((ext_vector_type(8))) unsigned short u16x8;

// workspace layout (bytes)
#define WS_CNT    0u
#define WS_SLOT   256u
#define WS_ASSIGN 33024u
#define WS_WT     65792u
#define WS_WTS2   98560u
#define WS_XB     131584u     // [2048][1024] bf16
#define WS_H      4325888u    // [6144][1024] bf16
#define WS_W1T    16908800u   // frag-linear bf16 weights; obuf after kfat2
#define WS_W3T    33686016u
#define WS_W2T    50463232u
#define WS_SW1T   67240448u
#define WS_SW3T   69337600u
#define WS_SW2T   71434752u
#define WS_NEED   73531904u
#define WS_OBUF   WS_W1T

__device__ __forceinline__ unsigned short f2bf(float f) {
    unsigned int u = __float_as_uint(f);
    return (unsigned short)((u + 0x7fffu + ((u >> 16) & 1u)) >> 16);
}
__device__ __forceinline__ float bf2f(unsigned short v) {
    return __uint_as_float(((unsigned int)v) << 16);
}

__device__ __forceinline__ void cp16(const void* g, void* l) {
    __builtin_amdgcn_global_load_lds((const __attribute__((address_space(1))) void*)g,
                                     (__attribute__((address_space(3))) void*)l, 16, 0, 0);
}

// ---------------- fat1: conv(w1,w3,sw1,sw3) [blocks 0..2303] + gate [2304..2815] ----------------
__global__ __launch_bounds__(256) void kfat1(
    const float* __restrict__ x, const float* __restrict__ gw,
    const float* __restrict__ w1, const float* __restrict__ w3,
    const float* __restrict__ sw1, const float* __restrict__ sw3,
    unsigned short* __restrict__ w1t, unsigned short* __restrict__ w3t,
    unsigned short* __restrict__ sw1t, unsigned short* __restrict__ sw3t,
    int* __restrict__ assign, float2* __restrict__ wts2, unsigned short* __restrict__ xb)
{
    __shared__ __align__(16) char smem[32768];
    int bid = blockIdx.x;
    int tid = threadIdx.x;
    if (bid < 2304) {
        int slab = bid >> 7, t = bid & 127;
        int r0 = (t >> 3) * 64, c0 = (t & 7) * 128;
        const float* src; unsigned short* dst;
        if (slab < 8)        { src = w1 + (size_t)slab * DIM * INTER;       dst = w1t + (size_t)slab * DIM * INTER; }
        else if (slab < 16)  { src = w3 + (size_t)(slab - 8) * DIM * INTER; dst = w3t + (size_t)(slab - 8) * DIM * INTER; }
        else if (slab == 16) { src = sw1; dst = sw1t; }
        else                 { src = sw3; dst = sw3t; }

        int w = tid >> 6, l = tid & 63;
        size_t lanoff = (size_t)(l >> 5) * 4096 + (size_t)(l & 31) * 16;
        const char* gbase = (const char*)src + (size_t)r0 * 4096 + (size_t)c0 * 4;
        #pragma unroll
        for (int i = 0; i < 8; ++i)
            cp16(gbase + (size_t)(w * 16 + i * 2) * 4096 + lanoff, smem + (w * 16 + i * 2) * 512);
        asm volatile("s_waitcnt vmcnt(0)" ::: "memory");
        __builtin_amdgcn_sched_barrier(0);
        __builtin_amdgcn_s_barrier();
        __builtin_amdgcn_sched_barrier(0);
        const float* ldsf = (const float*)smem;
        #pragma unroll
        for (int i = 0; i < 4; ++i) {
            int f = w * 4 + i;
            int ntl = f >> 1, ktl = f & 1;
            u16x8 o;
            #pragma unroll
            for (int j = 0; j < 8; ++j)
                o[j] = f2bf(ldsf[(ktl * 32 + (l >> 4) * 8 + j) * 128 + ntl * 16 + (l & 15)]);
            size_t off = ((size_t)((c0 >> 4) + ntl) * 32 + (r0 >> 5) + ktl) * 512 + l * 8;
            *(u16x8*)(dst + off) = o;
        }
        return;
    }
    // ---- gate ----
    int wid = tid >> 6, lane = tid & 63;
    int t = (bid - 2304) * 4 + wid;
    const float* xrow = x + (size_t)t * DIM;

    float xr[16];
    float acc[8] = {0.f,0.f,0.f,0.f,0.f,0.f,0.f,0.f};
    #pragma unroll
    for (int j = 0; j < 16; ++j) {
        float xv = xrow[j * 64 + lane];
        xr[j] = xv;
        const f32x4* g = (const f32x4*)(gw + (size_t)(j * 64 + lane) * 8);
        f32x4 g0 = g[0], g1 = g[1];
        acc[0] += xv * g0[0]; acc[1] += xv * g0[1]; acc[2] += xv * g0[2]; acc[3] += xv * g0[3];
        acc[4] += xv * g1[0]; acc[5] += xv * g1[1]; acc[6] += xv * g1[2]; acc[7] += xv * g1[3];
    }
    #pragma unroll
    for (int j = 0; j < 16; ++j) xb[(size_t)t * DIM + j * 64 + lane] = f2bf(xr[j]);

    #pragma unroll
    for (int e = 0; e < 8; ++e) {
        float v = acc[e];
        v += __shfl_xor(v, 1);  v += __shfl_xor(v, 2);  v += __shfl_xor(v, 4);
        v += __shfl_xor(v, 8);  v += __shfl_xor(v, 16); v += __shfl_xor(v, 32);
        acc[e] = v;
    }
    float mx = acc[0];
    #pragma unroll
    for (int e = 1; e < 8; ++e) mx = fmaxf(mx, acc[e]);
    float p[8]; float se = 0.f;
    #pragma unroll
    for (int e = 0; e < 8; ++e) { p[e] = expf(acc[e] - mx); se += p[e]; }
    float inv = 1.0f / se;
    int i0 = 0; float b0 = p[0];
    #pragma unroll
    for (int e = 1; e < 8; ++e) if (p[e] > b0) { b0 = p[e]; i0 = e; }
    int i1 = -1; float b1 = -1.f;
    #pragma unroll
    for (int e = 0; e < 8; ++e) if (e != i0 && p[e] > b1) { b1 = p[e]; i1 = e; }
    if (lane == 0) {
        assign[t] = i0 | (i1 << 8);
        wts2[t] = make_float2(b0 * inv, b1 * inv);
    }
}

// ---------------- scatter: 8 blocks, one expert each (redundant histogram) ----------------
__global__ __launch_bounds__(256) void kscatter(const int* __restrict__ assign,
                                                const float2* __restrict__ wts2,
                                                int* __restrict__ cnt,
                                                int* __restrict__ slots,
                                                float* __restrict__ wts)
{
    int myE = blockIdx.x;      // 0..7
    __shared__ int h[8];
    __shared__ int pos;
    int tid = threadIdx.x, lane = tid & 63;
    if (tid < 8) h[tid] = 0;
    __syncthreads();

    // pass 1: full histogram (redundant per block; 8 KB L2-hot)
    for (int base = 0; base < NT; base += 256) {
        int a = assign[base + tid];
        int e0 = a & 255, e1 = (a >> 8) & 255;
        #pragma unroll
        for (int e = 0; e < 8; ++e) {
            unsigned long long m0 = __ballot(e0 == e);
            unsigned long long m1 = __ballot(e1 == e);
            if (lane == 0) {
                int c = __popcll(m0) + __popcll(m1);
                if (c) atomicAdd(&h[e], c);
            }
        }
    }
    __syncthreads();
    if (tid == 0) {
        int run = 0;
        for (int e = 0; e < myE; ++e) run += h[e];
        pos = run;
        if (myE == 0) {
            int r2 = 0;
            #pragma unroll
            for (int e = 0; e < 8; ++e) { cnt[8 + e] = r2; cnt[e] = h[e]; r2 += h[e]; }
            cnt[16] = r2;
        }
    }
    __syncthreads();

    // pass 2: compact only expert myE
    for (int base = 0; base < NT; base += 256) {
        int t = base + tid;
        int a = assign[t];
        float2 w = wts2[t];
        int e0 = a & 255, e1 = (a >> 8) & 255;
        unsigned long long lt = (1ull << lane) - 1ull;
        unsigned long long m0 = __ballot(e0 == myE);
        unsigned long long m1 = __ballot(e1 == myE);
        int c = __popcll(m0) + __popcll(m1);
        int b = 0;
        if (lane == 0 && c) b = atomicAdd(&pos, c);
        b = __shfl(b, 0);
        if (e0 == myE) { int r = __popcll(m0 & lt);                 slots[b + r] = t * 2;     wts[b + r] = w.x; }
        if (e1 == myE) { int r = __popcll(m0) + __popcll(m1 & lt);  slots[b + r] = t * 2 + 1; wts[b + r] = w.y; }
    }
}

// ---------------- fat2: GEMM1 (z<9) + conv(w2,sw2) (z>=9, x<8) ----------------
// GEMM1: BM=128 BN=64 BK=64; 4 waves 2x2. A LDS dbuf (cp16+swizzle); B depth-2
// register prefetch from frag-linear weights.
__global__ __launch_bounds__(256) void kfat2(
    const unsigned short* __restrict__ xb,
    const unsigned short* __restrict__ w1t, const unsigned short* __restrict__ w3t,
    const unsigned short* __restrict__ sw1t, const unsigned short* __restrict__ sw3t,
    const int* __restrict__ cnt, const int* __restrict__ slots,
    unsigned short* __restrict__ hbuf,
    const float* __restrict__ w2, const float* __restrict__ sw2,
    unsigned short* __restrict__ w2t, unsigned short* __restrict__ sw2t)
{
    __shared__ __align__(16) char smem[34048];
    int z = blockIdx.z;
    int tid = threadIdx.x;
    if (z >= 9) {
        if (blockIdx.x >= 8) return;
        int slab = z - 9;
        const float* src; unsigned short* dst;
        if (slab < 8) { src = w2 + (size_t)slab * DIM * INTER; dst = w2t + (size_t)slab * DIM * INTER; }
        else          { src = sw2; dst = sw2t; }
        int r0 = blockIdx.y * 64, c0 = blockIdx.x * 128;

        int w = tid >> 6, l = tid & 63;
        size_t lanoff = (size_t)(l >> 5) * 4096 + (size_t)(l & 31) * 16;
        const char* gbase = (const char*)src + (size_t)r0 * 4096 + (size_t)c0 * 4;
        #pragma unroll
        for (int i = 0; i < 8; ++i)
            cp16(gbase + (size_t)(w * 16 + i * 2) * 4096 + lanoff, smem + (w * 16 + i * 2) * 512);
        asm volatile("s_waitcnt vmcnt(0)" ::: "memory");
        __builtin_amdgcn_sched_barrier(0);
        __builtin_amdgcn_s_barrier();
        __builtin_amdgcn_sched_barrier(0);
        const float* ldsf = (const float*)smem;
        #pragma unroll
        for (int i = 0; i < 4; ++i) {
            int f = w * 4 + i;
            int ntl = f >> 1, ktl = f & 1;
            u16x8 o;
            #pragma unroll
            for (int j = 0; j < 8; ++j)
                o[j] = f2bf(ldsf[(ktl * 32 + (l >> 4) * 8 + j) * 128 + ntl * 16 + (l & 15)]);
            size_t off = ((size_t)((c0 >> 4) + ntl) * 32 + (r0 >> 5) + ktl) * 512 + l * 8;
            *(u16x8*)(dst + off) = o;
        }
        return;
    }

    int e = z;
    int m0 = blockIdx.y * 128;
    int n0 = blockIdx.x * 64;
    int n_rows, lbase;
    if (e < 8) { n_rows = cnt[e]; lbase = cnt[8 + e]; } else { n_rows = NT; lbase = 0; }
    if (m0 >= n_rows) return;
    int rm = min(128, n_rows - m0);

    const unsigned short* b1p = (e < 8) ? (w1t + (size_t)e * DIM * INTER) : sw1t;
    const unsigned short* b3p = (e < 8) ? (w3t + (size_t)e * DIM * INTER) : sw3t;

    char* sA = smem;                       // [2][16384] A dbuf
    int* rowTok  = (int*)(smem + 32768);
    int* rowSlot = (int*)(smem + 33280);

    if (tid < 128) {
        int r = m0 + min(tid, rm - 1);
        int slot, tok;
        if (e < 8) { slot = slots[lbase + r]; tok = slot >> 1; }
        else       { tok = r; slot = 4096 + r; }
        rowTok[tid] = tok;
        rowSlot[tid] = slot;
    }
    __syncthreads();

    int wid = tid >> 6, lane = tid & 63;
    int wr = wid >> 1, wc = wid & 1;
    int swz_st = (((lane & 7) ^ (lane >> 3)) - (lane & 7)) * 16;

    const char* pA[4];
    #pragma unroll
    for (int q = 0; q < 4; ++q) {
        int row = (q * 4 + wid) * 8 + (lane >> 3);
        pA[q] = (const char*)(xb + (size_t)rowTok[row] * DIM) + (lane & 7) * 16 + swz_st;
    }
    const char* pB1[2]; const char* pB3[2];
    #pragma unroll
    for (int n = 0; n < 2; ++n) {
        int nt = (n0 >> 4) + wc * 2 + n;
        pB1[n] = (const char*)b1p + (size_t)nt * 32768 + lane * 16;
        pB3[n] = (const char*)b3p + (size_t)nt * 32768 + lane * 16;
    }

    int loA[2];
    #pragma unroll
    for (int ks = 0; ks < 2; ++ks) {
        int ch = ((ks * 4) + (lane >> 4)) ^ (lane & 7);
        loA[ks] = (wr * 64 + (lane & 15)) * 128 + ch * 16;
    }

    f32x4 acc1[4][2], acc3[4][2];
    #pragma unroll
    for (int m = 0; m < 4; ++m)
        #pragma unroll
        for (int n = 0; n < 2; ++n) { acc1[m][n] = (f32x4){0.f,0.f,0.f,0.f}; acc3[m][n] = (f32x4){0.f,0.f,0.f,0.f}; }

    s16x8 br1[2][2][2], br3[2][2][2];   // [slot][n][ks]

    // prologue: A0 -> sA[0]; B0 -> br[0]; B1 -> br[1]
    #pragma unroll
    for (int q = 0; q < 4; ++q) { cp16(pA[q], sA + (q * 4 + wid) * 1024); pA[q] += 128; }
    #pragma unroll
    for (int n = 0; n < 2; ++n)
        #pragma unroll
        for (int ks = 0; ks < 2; ++ks) {
            br1[0][n][ks] = *(const s16x8*)(pB1[n] + ks * 1024);
            br3[0][n][ks] = *(const s16x8*)(pB3[n] + ks * 1024);
        }
    #pragma unroll
    for (int n = 0; n < 2; ++n)
        #pragma unroll
        for (int ks = 0; ks < 2; ++ks) {
            br1[1][n][ks] = *(const s16x8*)(pB1[n] + (2 + ks) * 1024);
            br3[1][n][ks] = *(const s16x8*)(pB3[n] + (2 + ks) * 1024);
        }

    for (int tt = 0; tt < 7; ++tt) {
        #pragma unroll
        for (int half = 0; half < 2; ++half) {
            #pragma unroll
            for (int q = 0; q < 4; ++q) {
                cp16(pA[q], sA + (half ^ 1) * 16384 + (q * 4 + wid) * 1024);
                pA[q] += 128;
            }
            asm volatile("s_waitcnt vmcnt(12)" ::: "memory");
            __builtin_amdgcn_sched_barrier(0);
            __builtin_amdgcn_s_barrier();
            __builtin_amdgcn_sched_barrier(0);

            #pragma unroll
            for (int ks = 0; ks < 2; ++ks) {
                s16x8 a[4];
                #pragma unroll
                for (int m = 0; m < 4; ++m)
                    a[m] = *(const s16x8*)(sA + half * 16384 + m * 2048 + loA[ks]);
                #pragma unroll
                for (int n = 0; n < 2; ++n) {
                    #pragma unroll
                    for (int m = 0; m < 4; ++m) {
                        acc1[m][n] = __builtin_amdgcn_mfma_f32_16x16x32_bf16(a[m], br1[half][n][ks], acc1[m][n], 0, 0, 0);
                        acc3[m][n] = __builtin_amdgcn_mfma_f32_16x16x32_bf16(a[m], br3[half][n][ks], acc3[m][n], 0, 0, 0);
                    }
                }
            }
            #pragma unroll
            for (int n = 0; n < 2; ++n)
                #pragma unroll
                for (int ks = 0; ks < 2; ++ks) {
                    br1[half][n][ks] = *(const s16x8*)(pB1[n] + (half * 2 + 4 + ks) * 1024);
                    br3[half][n][ks] = *(const s16x8*)(pB3[n] + (half * 2 + 4 + ks) * 1024);
                }
            __builtin_amdgcn_sched_barrier(0);
            __builtin_amdgcn_s_barrier();
            __builtin_amdgcn_sched_barrier(0);
        }
        #pragma unroll
        for (int n = 0; n < 2; ++n) { pB1[n] += 4096; pB3[n] += 4096; }
    }
    // t=14
    #pragma unroll
    for (int q = 0; q < 4; ++q) cp16(pA[q], sA + 16384 + (q * 4 + wid) * 1024);
    asm volatile("s_waitcnt vmcnt(12)" ::: "memory");
    __builtin_amdgcn_sched_barrier(0);
    __builtin_amdgcn_s_barrier();
    __builtin_amdgcn_sched_barrier(0);
    #pragma unroll
    for (int ks = 0; ks < 2; ++ks) {
        s16x8 a[4];
        #pragma unroll
        for (int m = 0; m < 4; ++m)
            a[m] = *(const s16x8*)(sA + m * 2048 + loA[ks]);
        #pragma unroll
        for (int n = 0; n < 2; ++n)
            #pragma unroll
            for (int m = 0; m < 4; ++m) {
                acc1[m][n] = __builtin_amdgcn_mfma_f32_16x16x32_bf16(a[m], br1[0][n][ks], acc1[m][n], 0, 0, 0);
                acc3[m][n] = __builtin_amdgcn_mfma_f32_16x16x32_bf16(a[m], br3[0][n][ks], acc3[m][n], 0, 0, 0);
            }
    }
    __builtin_amdgcn_sched_barrier(0);
    __builtin_amdgcn_s_barrier();
    __builtin_amdgcn_sched_barrier(0);
    // t=15
    asm volatile("s_waitcnt vmcnt(0)" ::: "memory");
    __builtin_amdgcn_sched_barrier(0);
    __builtin_amdgcn_s_barrier();
    __builtin_amdgcn_sched_barrier(0);
    #pragma unroll
    for (int ks = 0; ks < 2; ++ks) {
        s16x8 a[4];
        #pragma unroll
        for (int m = 0; m < 4; ++m)
            a[m] = *(const s16x8*)(sA + 16384 + m * 2048 + loA[ks]);
        #pragma unroll
        for (int n = 0; n < 2; ++n)
            #pragma unroll
            for (int m = 0; m < 4; ++m) {
                acc1[m][n] = __builtin_amdgcn_mfma_f32_16x16x32_bf16(a[m], br1[1][n][ks], acc1[m][n], 0, 0, 0);
                acc3[m][n] = __builtin_amdgcn_mfma_f32_16x16x32_bf16(a[m], br3[1][n][ks], acc3[m][n], 0, 0, 0);
            }
    }

    #pragma unroll
    for (int m = 0; m < 4; ++m) {
        int rbase = wr * 64 + m * 16 + (lane >> 4) * 4;
        #pragma unroll
        for (int r = 0; r < 4; ++r) {
            int row = rbase + r;
            if (row < rm) {
                int hrow = rowSlot[row];
                #pragma unroll
                for (int n = 0; n < 2; ++n) {
                    float v1 = acc1[m][n][r], v3 = acc3[m][n][r];
                    float hv = (v1 / (1.0f + __expf(-v1))) * v3;
                    int col = n0 + wc * 32 + n * 16 + (lane & 15);
                    hbuf[(size_t)hrow * INTER + col] = f2bf(hv);
                }
            }
        }
    }
}

// ---------------- GEMM2: obuf[slot] = h W2 (A LDS dbuf; B depth-2 reg prefetch) ----------------
__global__ __launch_bounds__(256) void kgemm2(
    const unsigned short* __restrict__ hbuf,
    const unsigned short* __restrict__ w2t, const unsigned short* __restrict__ sw2t,
    const int* __restrict__ cnt, const int* __restrict__ slots,
    unsigned short* __restrict__ obuf)
{
    int e = blockIdx.z;
    int m0 = blockIdx.y * 128;
    int n0 = blockIdx.x * 64;
    int n_rows, lbase;
    if (e < 8) { n_rows = cnt[e]; lbase = cnt[8 + e]; } else { n_rows = NT; lbase = 0; }
    if (m0 >= n_rows) return;
    int rm = min(128, n_rows - m0);
    const unsigned short* bp = (e < 8) ? (w2t + (size_t)e * DIM * INTER) : sw2t;

    __shared__ __align__(16) char sA[2][16384];
    __shared__ int rowH[128];

    int tid = threadIdx.x;
    if (tid < 128) {
        int r = m0 + min(tid, rm - 1);
        rowH[tid] = (e < 8) ? slots[lbase + r] : (4096 + r);
    }
    __syncthreads();

    int wid = tid >> 6, lane = tid & 63;
    int wr = wid >> 1, wc = wid & 1;
    int swz_st = (((lane & 7) ^ (lane >> 3)) - (lane & 7)) * 16;

    const char* pA[4];
    #pragma unroll
    for (int q = 0; q < 4; ++q) {
        int row = (q * 4 + wid) * 8 + (lane >> 3);
        pA[q] = (const char*)(hbuf + (size_t)rowH[row] * INTER) + (lane & 7) * 16 + swz_st;
    }
    const char* pB[2];
    #pragma unroll
    for (int n = 0; n < 2; ++n) {
        int nt = (n0 >> 4) + wc * 2 + n;
        pB[n] = (const char*)bp + (size_t)nt * 32768 + lane * 16;
    }

    int loA[2];
    #pragma unroll
    for (int ks = 0; ks < 2; ++ks) {
        int ch = ((ks * 4) + (lane >> 4)) ^ (lane & 7);
        loA[ks] = (wr * 64 + (lane & 15)) * 128 + ch * 16;
    }

    f32x4 acc[4][2];
    #pragma unroll
    for (int m = 0; m < 4; ++m)
        #pragma unroll
        for (int n = 0; n < 2; ++n) acc[m][n] = (f32x4){0.f,0.f,0.f,0.f};

    s16x8 br[2][2][2];

    #pragma unroll
    for (int q = 0; q < 4; ++q) { cp16(pA[q], (char*)sA + (q * 4 + wid) * 1024); pA[q] += 128; }
    #pragma unroll
    for (int n = 0; n < 2; ++n)
        #pragma unroll
        for (int ks = 0; ks < 2; ++ks)
            br[0][n][ks] = *(const s16x8*)(pB[n] + ks * 1024);
    #pragma unroll
    for (int n = 0; n < 2; ++n)
        #pragma unroll
        for (int ks = 0; ks < 2; ++ks)
            br[1][n][ks] = *(const s16x8*)(pB[n] + (2 + ks) * 1024);

    for (int tt = 0; tt < 7; ++tt) {
        #pragma unroll
        for (int half = 0; half < 2; ++half) {
            #pragma unroll
            for (int q = 0; q < 4; ++q) {
                cp16(pA[q], (char*)sA + (half ^ 1) * 16384 + (q * 4 + wid) * 1024);
                pA[q] += 128;
            }
            asm volatile("s_waitcnt vmcnt(8)" ::: "memory");
            __builtin_amdgcn_sched_barrier(0);
            __builtin_amdgcn_s_barrier();
            __builtin_amdgcn_sched_barrier(0);

            #pragma unroll
            for (int ks = 0; ks < 2; ++ks) {
                s16x8 a[4];
                #pragma unroll
                for (int m = 0; m < 4; ++m)
                    a[m] = *(const s16x8*)((const char*)sA + half * 16384 + m * 2048 + loA[ks]);
                #pragma unroll
                for (int n = 0; n < 2; ++n)
                    #pragma unroll
                    for (int m = 0; m < 4; ++m)
                        acc[m][n] = __builtin_amdgcn_mfma_f32_16x16x32_bf16(a[m], br[half][n][ks], acc[m][n], 0, 0, 0);
            }
            #pragma unroll
            for (int n = 0; n < 2; ++n)
                #pragma unroll
                for (int ks = 0; ks < 2; ++ks)
                    br[half][n][ks] = *(const s16x8*)(pB[n] + (half * 2 + 4 + ks) * 1024);
            __builtin_amdgcn_sched_barrier(0);
            __builtin_amdgcn_s_barrier();
            __builtin_amdgcn_sched_barrier(0);
        }
        #pragma unroll
        for (int n = 0; n < 2; ++n) pB[n] += 4096;
    }
    // t=14
    #pragma unroll
    for (int q = 0; q < 4; ++q) cp16(pA[q], (char*)sA + 16384 + (q * 4 + wid) * 1024);
    asm volatile("s_waitcnt vmcnt(8)" ::: "memory");
    __builtin_amdgcn_sched_barrier(0);
    __builtin_amdgcn_s_barrier();
    __builtin_amdgcn_sched_barrier(0);
    #pragma unroll
    for (int ks = 0; ks < 2; ++ks) {
        s16x8 a[4];
        #pragma unroll
        for (int m = 0; m < 4; ++m)
            a[m] = *(const s16x8*)((const char*)sA + m * 2048 + loA[ks]);
        #pragma unroll
        for (int n = 0; n < 2; ++n)
            #pragma unroll
            for (int m = 0; m < 4; ++m)
                acc[m][n] = __builtin_amdgcn_mfma_f32_16x16x32_bf16(a[m], br[0][n][ks], acc[m][n], 0, 0, 0);
    }
    __builtin_amdgcn_sched_barrier(0);
    __builtin_amdgcn_s_barrier();
    __builtin_amdgcn_sched_barrier(0);
    // t=15
    asm volatile("s_waitcnt vmcnt(0)" ::: "memory");
    __builtin_amdgcn_sched_barrier(0);
    __builtin_amdgcn_s_barrier();
    __builtin_amdgcn_sched_barrier(0);
    #pragma unroll
    for (int ks = 0; ks < 2; ++ks) {
        s16x8 a[4];
        #pragma unroll
        for (int m = 0; m < 4; ++m)
            a[m] = *(const s16x8*)((const char*)sA + 16384 + m * 2048 + loA[ks]);
        #pragma unroll
        for (int n = 0; n < 2; ++n)
            #pragma unroll
            for (int m = 0; m < 4; ++m)
                acc[m][n] = __builtin_amdgcn_mfma_f32_16x16x32_bf16(a[m], br[1][n][ks], acc[m][n], 0, 0, 0);
    }

    #pragma unroll
    for (int m = 0; m < 4; ++m) {
        int rbase = wr * 64 + m * 16 + (lane >> 4) * 4;
        #pragma unroll
        for (int r = 0; r < 4; ++r) {
            int row = rbase + r;
            if (row < rm) {
                int orow = rowH[row];
                #pragma unroll
                for (int n = 0; n < 2; ++n) {
                    int col = n0 + wc * 32 + n * 16 + (lane & 15);
                    obuf[(size_t)orow * DIM + col] = f2bf(acc[m][n][r]);
                }
            }
        }
    }
}

// ---------------- combine ----------------
__global__ __launch_bounds__(256) void kcombine(const unsigned short* __restrict__ obuf,
                                                const float2* __restrict__ wts2,
                                                float* __restrict__ out)
{
    int gid = blockIdx.x * 256 + threadIdx.x;
    int t = gid >> 7;
    int d0 = (gid & 127) * 8;
    float2 w = wts2[t];
    u16x8 r0 = *(const u16x8*)&obuf[(size_t)(2 * t)     * DIM + d0];
    u16x8 r1 = *(const u16x8*)&obuf[(size_t)(2 * t + 1) * DIM + d0];
    u16x8 rs = *(const u16x8*)&obuf[(size_t)(4096 + t)  * DIM + d0];
    f32x4 o0, o1;
    #pragma unroll
    for (int j = 0; j < 4; ++j) o0[j] = w.x * bf2f(r0[j]) + w.y * bf2f(r1[j]) + bf2f(rs[j]);
    #pragma unroll
    for (int j = 0; j < 4; ++j) o1[j] = w.x * bf2f(r0[4+j]) + w.y * bf2f(r1[4+j]) + bf2f(rs[4+j]);
    f32x4* dst = (f32x4*)&out[(size_t)t * DIM + d0];
    dst[0] = o0; dst[1] = o1;
}

extern "C" void kernel_launch(void* const* d_in, const int* in_sizes, int n_in,
                              void* d_out, int out_size, void* d_ws, size_t ws_size,
                              hipStream_t stream) {
    const float* x      = (const float*)d_in[0];
    const float* gate_w = (const float*)d_in[1];
    const float* w1     = (const float*)d_in[2];
    const float* w2     = (const float*)d_in[3];
    const float* w3     = (const float*)d_in[4];
    const float* sw1    = (const float*)d_in[5];
    const float* sw2    = (const float*)d_in[6];
    const float* sw3    = (const float*)d_in[7];
    float* out = (float*)d_out;

    if (ws_size < (size_t)WS_NEED) return;

    char* ws = (char*)d_ws;
    int*            cnt      = (int*)(ws + WS_CNT);
    int*            slots    = (int*)(ws + WS_SLOT);
    int*            assign   = (int*)(ws + WS_ASSIGN);
    float*          wts      = (float*)(ws + WS_WT);
    float2*         wts2     = (float2*)(ws + WS_WTS2);
    unsigned short* xb       = (unsigned short*)(ws + WS_XB);
    unsigned short* hbuf     = (unsigned short*)(ws + WS_H);
    unsigned short* w1t      = (unsigned short*)(ws + WS_W1T);
    unsigned short* w3t      = (unsigned short*)(ws + WS_W3T);
    unsigned short* w2t      = (unsigned short*)(ws + WS_W2T);
    unsigned short* sw1t     = (unsigned short*)(ws + WS_SW1T);
    unsigned short* sw3t     = (unsigned short*)(ws + WS_SW3T);
    unsigned short* sw2t     = (unsigned short*)(ws + WS_SW2T);
    unsigned short* obuf     = (unsigned short*)(ws + WS_OBUF);

    kfat1<<<dim3(2816), 256, 0, stream>>>(x, gate_w, w1, w3, sw1, sw3,
                                          w1t, w3t, sw1t, sw3t, assign, wts2, xb);
    kscatter<<<dim3(8), 256, 0, stream>>>(assign, wts2, cnt, slots, wts);
    kfat2<<<dim3(16, 16, 18), 256, 0, stream>>>(xb, w1t, w3t, sw1t, sw3t, cnt, slots, hbuf,
                                                w2, sw2, w2t, sw2t);
    kgemm2<<<dim3(16, 16, 9), 256, 0, stream>>>(hbuf, w2t, sw2t, cnt, slots, obuf);
    kcombine<<<dim3(1024), 256, 0, stream>>>(obuf, wts2, out);
}

// Round 20
// 113.920 us; speedup vs baseline: 1.1651x; 1.0023x over previous
//
#include <hip/hip_runtime.h>
#include <hip/hip_bf16.h>
#include <cstdint>
#include <cstddef>

#define DIM   1024
#define INTER 1024
#define NT    2048      // tokens

typedef __attribute__((ext_vector_type(4))) float  f32x4;
typedef __attribute__((ext_vector_type(8))) short  s16x8;
typedef __attribute__((ext_vector_type(8))) unsigned short u16x8;

// workspace layout (bytes)
#define WS_CNT    0u
#define WS_SLOT   256u
#define WS_ASSIGN 33024u
#define WS_WT     65792u
#define WS_WTS2   98560u
#define WS_XB     131584u     // [2048][1024] bf16
#define WS_H      4325888u    // [6144][1024] bf16
#define WS_W1T    16908800u   // frag-linear bf16 weights; obuf after kfat2
#define WS_W3T    33686016u
#define WS_W2T    50463232u
#define WS_SW1T   67240448u
#define WS_SW3T   69337600u
#define WS_SW2T   71434752u
#define WS_NEED   73531904u
#define WS_OBUF   WS_W1T

__device__ __forceinline__ unsigned short f2bf(float f) {
    unsigned int u = __float_as_uint(f);
    return (unsigned short)((u + 0x7fffu + ((u >> 16) & 1u)) >> 16);
}
__device__ __forceinline__ float bf2f(unsigned short v) {
    return __uint_as_float(((unsigned int)v) << 16);
}

__device__ __forceinline__ void cp16(const void* g, void* l) {
    __builtin_amdgcn_global_load_lds((const __attribute__((address_space(1))) void*)g,
                                     (__attribute__((address_space(3))) void*)l, 16, 0, 0);
}

// ---- conv body with SPLIT DRAIN: wave w stages rows [8w,8w+8) then
// [32+8w,32+8w+8); vmcnt(4)+barrier -> ktl=0 frags (rows 0-31) convert while
// second half is in flight; vmcnt(0)+barrier -> ktl=1 frags (rows 32-63).
__device__ __forceinline__ void conv_tile_split(const float* __restrict__ src,
                                                unsigned short* __restrict__ dst,
                                                int r0, int c0, char* smem,
                                                int w, int l)
{
    size_t lanoff = (size_t)(l >> 5) * 4096 + (size_t)(l & 31) * 16;
    const char* gbase = (const char*)src + (size_t)r0 * 4096 + (size_t)c0 * 4;
    #pragma unroll
    for (int i = 0; i < 4; ++i)
        cp16(gbase + (size_t)(w * 8 + i * 2) * 4096 + lanoff, smem + (w * 8 + i * 2) * 512);
    #pragma unroll
    for (int i = 0; i < 4; ++i)
        cp16(gbase + (size_t)(32 + w * 8 + i * 2) * 4096 + lanoff, smem + (32 + w * 8 + i * 2) * 512);

    const float* ldsf = (const float*)smem;
    int cl = l & 15, kg = l >> 4;

    asm volatile("s_waitcnt vmcnt(4)" ::: "memory");   // first-half rows landed
    __builtin_amdgcn_sched_barrier(0);
    __builtin_amdgcn_s_barrier();
    __builtin_amdgcn_sched_barrier(0);
    #pragma unroll
    for (int i = 0; i < 4; i += 2) {                   // ktl = 0 frags
        int f = w * 4 + i;
        int ntl = f >> 1;
        u16x8 o;
        #pragma unroll
        for (int j = 0; j < 8; ++j)
            o[j] = f2bf(ldsf[(kg * 8 + j) * 128 + ntl * 16 + cl]);
        size_t off = ((size_t)((c0 >> 4) + ntl) * 32 + (r0 >> 5)) * 512 + l * 8;
        *(u16x8*)(dst + off) = o;
    }
    asm volatile("s_waitcnt vmcnt(0)" ::: "memory");   // second-half rows landed
    __builtin_amdgcn_sched_barrier(0);
    __builtin_amdgcn_s_barrier();
    __builtin_amdgcn_sched_barrier(0);
    #pragma unroll
    for (int i = 1; i < 4; i += 2) {                   // ktl = 1 frags
        int f = w * 4 + i;
        int ntl = f >> 1;
        u16x8 o;
        #pragma unroll
        for (int j = 0; j < 8; ++j)
            o[j] = f2bf(ldsf[(32 + kg * 8 + j) * 128 + ntl * 16 + cl]);
        size_t off = ((size_t)((c0 >> 4) + ntl) * 32 + (r0 >> 5) + 1) * 512 + l * 8;
        *(u16x8*)(dst + off) = o;
    }
}

// ---------------- fat1: conv(w1,w3,sw1,sw3) [blocks 0..2303] + gate [2304..2815] ----------------
__global__ __launch_bounds__(256) void kfat1(
    const float* __restrict__ x, const float* __restrict__ gw,
    const float* __restrict__ w1, const float* __restrict__ w3,
    const float* __restrict__ sw1, const float* __restrict__ sw3,
    unsigned short* __restrict__ w1t, unsigned short* __restrict__ w3t,
    unsigned short* __restrict__ sw1t, unsigned short* __restrict__ sw3t,
    int* __restrict__ assign, float2* __restrict__ wts2, unsigned short* __restrict__ xb)
{
    __shared__ __align__(16) char smem[32768];
    int bid = blockIdx.x;
    int tid = threadIdx.x;
    if (bid < 2304) {
        int slab = bid >> 7, t = bid & 127;
        int r0 = (t >> 3) * 64, c0 = (t & 7) * 128;
        const float* src; unsigned short* dst;
        if (slab < 8)        { src = w1 + (size_t)slab * DIM * INTER;       dst = w1t + (size_t)slab * DIM * INTER; }
        else if (slab < 16)  { src = w3 + (size_t)(slab - 8) * DIM * INTER; dst = w3t + (size_t)(slab - 8) * DIM * INTER; }
        else if (slab == 16) { src = sw1; dst = sw1t; }
        else                 { src = sw3; dst = sw3t; }
        conv_tile_split(src, dst, r0, c0, smem, tid >> 6, tid & 63);
        return;
    }
    // ---- gate ----
    int wid = tid >> 6, lane = tid & 63;
    int t = (bid - 2304) * 4 + wid;
    const float* xrow = x + (size_t)t * DIM;

    float xr[16];
    float acc[8] = {0.f,0.f,0.f,0.f,0.f,0.f,0.f,0.f};
    #pragma unroll
    for (int j = 0; j < 16; ++j) {
        float xv = xrow[j * 64 + lane];
        xr[j] = xv;
        const f32x4* g = (const f32x4*)(gw + (size_t)(j * 64 + lane) * 8);
        f32x4 g0 = g[0], g1 = g[1];
        acc[0] += xv * g0[0]; acc[1] += xv * g0[1]; acc[2] += xv * g0[2]; acc[3] += xv * g0[3];
        acc[4] += xv * g1[0]; acc[5] += xv * g1[1]; acc[6] += xv * g1[2]; acc[7] += xv * g1[3];
    }
    #pragma unroll
    for (int j = 0; j < 16; ++j) xb[(size_t)t * DIM + j * 64 + lane] = f2bf(xr[j]);

    #pragma unroll
    for (int e = 0; e < 8; ++e) {
        float v = acc[e];
        v += __shfl_xor(v, 1);  v += __shfl_xor(v, 2);  v += __shfl_xor(v, 4);
        v += __shfl_xor(v, 8);  v += __shfl_xor(v, 16); v += __shfl_xor(v, 32);
        acc[e] = v;
    }
    float mx = acc[0];
    #pragma unroll
    for (int e = 1; e < 8; ++e) mx = fmaxf(mx, acc[e]);
    float p[8]; float se = 0.f;
    #pragma unroll
    for (int e = 0; e < 8; ++e) { p[e] = expf(acc[e] - mx); se += p[e]; }
    float inv = 1.0f / se;
    int i0 = 0; float b0 = p[0];
    #pragma unroll
    for (int e = 1; e < 8; ++e) if (p[e] > b0) { b0 = p[e]; i0 = e; }
    int i1 = -1; float b1 = -1.f;
    #pragma unroll
    for (int e = 0; e < 8; ++e) if (e != i0 && p[e] > b1) { b1 = p[e]; i1 = e; }
    if (lane == 0) {
        assign[t] = i0 | (i1 << 8);
        wts2[t] = make_float2(b0 * inv, b1 * inv);
    }
}

// ---------------- scatter: 8 blocks, one expert each (redundant histogram) ----------------
__global__ __launch_bounds__(256) void kscatter(const int* __restrict__ assign,
                                                const float2* __restrict__ wts2,
                                                int* __restrict__ cnt,
                                                int* __restrict__ slots,
                                                float* __restrict__ wts)
{
    int myE = blockIdx.x;      // 0..7
    __shared__ int h[8];
    __shared__ int pos;
    int tid = threadIdx.x, lane = tid & 63;
    if (tid < 8) h[tid] = 0;
    __syncthreads();

    for (int base = 0; base < NT; base += 256) {
        int a = assign[base + tid];
        int e0 = a & 255, e1 = (a >> 8) & 255;
        #pragma unroll
        for (int e = 0; e < 8; ++e) {
            unsigned long long m0 = __ballot(e0 == e);
            unsigned long long m1 = __ballot(e1 == e);
            if (lane == 0) {
                int c = __popcll(m0) + __popcll(m1);
                if (c) atomicAdd(&h[e], c);
            }
        }
    }
    __syncthreads();
    if (tid == 0) {
        int run = 0;
        for (int e = 0; e < myE; ++e) run += h[e];
        pos = run;
        if (myE == 0) {
            int r2 = 0;
            #pragma unroll
            for (int e = 0; e < 8; ++e) { cnt[8 + e] = r2; cnt[e] = h[e]; r2 += h[e]; }
            cnt[16] = r2;
        }
    }
    __syncthreads();

    for (int base = 0; base < NT; base += 256) {
        int t = base + tid;
        int a = assign[t];
        float2 w = wts2[t];
        int e0 = a & 255, e1 = (a >> 8) & 255;
        unsigned long long lt = (1ull << lane) - 1ull;
        unsigned long long m0 = __ballot(e0 == myE);
        unsigned long long m1 = __ballot(e1 == myE);
        int c = __popcll(m0) + __popcll(m1);
        int b = 0;
        if (lane == 0 && c) b = atomicAdd(&pos, c);
        b = __shfl(b, 0);
        if (e0 == myE) { int r = __popcll(m0 & lt);                 slots[b + r] = t * 2;     wts[b + r] = w.x; }
        if (e1 == myE) { int r = __popcll(m0) + __popcll(m1 & lt);  slots[b + r] = t * 2 + 1; wts[b + r] = w.y; }
    }
}

// ---------------- fat2: GEMM1 (z<9) + conv(w2,sw2) (z>=9, x<8) ----------------
// GEMM1: BM=128 BN=64 BK=64; 4 waves 2x2. A LDS dbuf (cp16+swizzle); B depth-2
// register prefetch from frag-linear weights.
__global__ __launch_bounds__(256) void kfat2(
    const unsigned short* __restrict__ xb,
    const unsigned short* __restrict__ w1t, const unsigned short* __restrict__ w3t,
    const unsigned short* __restrict__ sw1t, const unsigned short* __restrict__ sw3t,
    const int* __restrict__ cnt, const int* __restrict__ slots,
    unsigned short* __restrict__ hbuf,
    const float* __restrict__ w2, const float* __restrict__ sw2,
    unsigned short* __restrict__ w2t, unsigned short* __restrict__ sw2t)
{
    __shared__ __align__(16) char smem[34048];
    int z = blockIdx.z;
    int tid = threadIdx.x;
    if (z >= 9) {
        if (blockIdx.x >= 8) return;
        int slab = z - 9;
        const float* src; unsigned short* dst;
        if (slab < 8) { src = w2 + (size_t)slab * DIM * INTER; dst = w2t + (size_t)slab * DIM * INTER; }
        else          { src = sw2; dst = sw2t; }
        conv_tile_split(src, dst, blockIdx.y * 64, blockIdx.x * 128, smem, tid >> 6, tid & 63);
        return;
    }

    int e = z;
    int m0 = blockIdx.y * 128;
    int n0 = blockIdx.x * 64;
    int n_rows, lbase;
    if (e < 8) { n_rows = cnt[e]; lbase = cnt[8 + e]; } else { n_rows = NT; lbase = 0; }
    if (m0 >= n_rows) return;
    int rm = min(128, n_rows - m0);

    const unsigned short* b1p = (e < 8) ? (w1t + (size_t)e * DIM * INTER) : sw1t;
    const unsigned short* b3p = (e < 8) ? (w3t + (size_t)e * DIM * INTER) : sw3t;

    char* sA = smem;                       // [2][16384] A dbuf
    int* rowTok  = (int*)(smem + 32768);
    int* rowSlot = (int*)(smem + 33280);

    if (tid < 128) {
        int r = m0 + min(tid, rm - 1);
        int slot, tok;
        if (e < 8) { slot = slots[lbase + r]; tok = slot >> 1; }
        else       { tok = r; slot = 4096 + r; }
        rowTok[tid] = tok;
        rowSlot[tid] = slot;
    }
    __syncthreads();

    int wid = tid >> 6, lane = tid & 63;
    int wr = wid >> 1, wc = wid & 1;
    int swz_st = (((lane & 7) ^ (lane >> 3)) - (lane & 7)) * 16;

    const char* pA[4];
    #pragma unroll
    for (int q = 0; q < 4; ++q) {
        int row = (q * 4 + wid) * 8 + (lane >> 3);
        pA[q] = (const char*)(xb + (size_t)rowTok[row] * DIM) + (lane & 7) * 16 + swz_st;
    }
    const char* pB1[2]; const char* pB3[2];
    #pragma unroll
    for (int n = 0; n < 2; ++n) {
        int nt = (n0 >> 4) + wc * 2 + n;
        pB1[n] = (const char*)b1p + (size_t)nt * 32768 + lane * 16;
        pB3[n] = (const char*)b3p + (size_t)nt * 32768 + lane * 16;
    }

    int loA[2];
    #pragma unroll
    for (int ks = 0; ks < 2; ++ks) {
        int ch = ((ks * 4) + (lane >> 4)) ^ (lane & 7);
        loA[ks] = (wr * 64 + (lane & 15)) * 128 + ch * 16;
    }

    f32x4 acc1[4][2], acc3[4][2];
    #pragma unroll
    for (int m = 0; m < 4; ++m)
        #pragma unroll
        for (int n = 0; n < 2; ++n) { acc1[m][n] = (f32x4){0.f,0.f,0.f,0.f}; acc3[m][n] = (f32x4){0.f,0.f,0.f,0.f}; }

    s16x8 br1[2][2][2], br3[2][2][2];   // [slot][n][ks]

    // prologue: A0 -> sA[0]; B0 -> br[0]; B1 -> br[1]
    #pragma unroll
    for (int q = 0; q < 4; ++q) { cp16(pA[q], sA + (q * 4 + wid) * 1024); pA[q] += 128; }
    #pragma unroll
    for (int n = 0; n < 2; ++n)
        #pragma unroll
        for (int ks = 0; ks < 2; ++ks) {
            br1[0][n][ks] = *(const s16x8*)(pB1[n] + ks * 1024);
            br3[0][n][ks] = *(const s16x8*)(pB3[n] + ks * 1024);
        }
    #pragma unroll
    for (int n = 0; n < 2; ++n)
        #pragma unroll
        for (int ks = 0; ks < 2; ++ks) {
            br1[1][n][ks] = *(const s16x8*)(pB1[n] + (2 + ks) * 1024);
            br3[1][n][ks] = *(const s16x8*)(pB3[n] + (2 + ks) * 1024);
        }

    for (int tt = 0; tt < 7; ++tt) {
        #pragma unroll
        for (int half = 0; half < 2; ++half) {
            #pragma unroll
            for (int q = 0; q < 4; ++q) {
                cp16(pA[q], sA + (half ^ 1) * 16384 + (q * 4 + wid) * 1024);
                pA[q] += 128;
            }
            asm volatile("s_waitcnt vmcnt(12)" ::: "memory");
            __builtin_amdgcn_sched_barrier(0);
            __builtin_amdgcn_s_barrier();
            __builtin_amdgcn_sched_barrier(0);

            #pragma unroll
            for (int ks = 0; ks < 2; ++ks) {
                s16x8 a[4];
                #pragma unroll
                for (int m = 0; m < 4; ++m)
                    a[m] = *(const s16x8*)(sA + half * 16384 + m * 2048 + loA[ks]);
                #pragma unroll
                for (int n = 0; n < 2; ++n) {
                    #pragma unroll
                    for (int m = 0; m < 4; ++m) {
                        acc1[m][n] = __builtin_amdgcn_mfma_f32_16x16x32_bf16(a[m], br1[half][n][ks], acc1[m][n], 0, 0, 0);
                        acc3[m][n] = __builtin_amdgcn_mfma_f32_16x16x32_bf16(a[m], br3[half][n][ks], acc3[m][n], 0, 0, 0);
                    }
                }
            }
            #pragma unroll
            for (int n = 0; n < 2; ++n)
                #pragma unroll
                for (int ks = 0; ks < 2; ++ks) {
                    br1[half][n][ks] = *(const s16x8*)(pB1[n] + (half * 2 + 4 + ks) * 1024);
                    br3[half][n][ks] = *(const s16x8*)(pB3[n] + (half * 2 + 4 + ks) * 1024);
                }
            __builtin_amdgcn_sched_barrier(0);
            __builtin_amdgcn_s_barrier();
            __builtin_amdgcn_sched_barrier(0);
        }
        #pragma unroll
        for (int n = 0; n < 2; ++n) { pB1[n] += 4096; pB3[n] += 4096; }
    }
    // t=14
    #pragma unroll
    for (int q = 0; q < 4; ++q) cp16(pA[q], sA + 16384 + (q * 4 + wid) * 1024);
    asm volatile("s_waitcnt vmcnt(12)" ::: "memory");
    __builtin_amdgcn_sched_barrier(0);
    __builtin_amdgcn_s_barrier();
    __builtin_amdgcn_sched_barrier(0);
    #pragma unroll
    for (int ks = 0; ks < 2; ++ks) {
        s16x8 a[4];
        #pragma unroll
        for (int m = 0; m < 4; ++m)
            a[m] = *(const s16x8*)(sA + m * 2048 + loA[ks]);
        #pragma unroll
        for (int n = 0; n < 2; ++n)
            #pragma unroll
            for (int m = 0; m < 4; ++m) {
                acc1[m][n] = __builtin_amdgcn_mfma_f32_16x16x32_bf16(a[m], br1[0][n][ks], acc1[m][n], 0, 0, 0);
                acc3[m][n] = __builtin_amdgcn_mfma_f32_16x16x32_bf16(a[m], br3[0][n][ks], acc3[m][n], 0, 0, 0);
            }
    }
    __builtin_amdgcn_sched_barrier(0);
    __builtin_amdgcn_s_barrier();
    __builtin_amdgcn_sched_barrier(0);
    // t=15
    asm volatile("s_waitcnt vmcnt(0)" ::: "memory");
    __builtin_amdgcn_sched_barrier(0);
    __builtin_amdgcn_s_barrier();
    __builtin_amdgcn_sched_barrier(0);
    #pragma unroll
    for (int ks = 0; ks < 2; ++ks) {
        s16x8 a[4];
        #pragma unroll
        for (int m = 0; m < 4; ++m)
            a[m] = *(const s16x8*)(sA + 16384 + m * 2048 + loA[ks]);
        #pragma unroll
        for (int n = 0; n < 2; ++n)
            #pragma unroll
            for (int m = 0; m < 4; ++m) {
                acc1[m][n] = __builtin_amdgcn_mfma_f32_16x16x32_bf16(a[m], br1[1][n][ks], acc1[m][n], 0, 0, 0);
                acc3[m][n] = __builtin_amdgcn_mfma_f32_16x16x32_bf16(a[m], br3[1][n][ks], acc3[m][n], 0, 0, 0);
            }
    }

    #pragma unroll
    for (int m = 0; m < 4; ++m) {
        int rbase = wr * 64 + m * 16 + (lane >> 4) * 4;
        #pragma unroll
        for (int r = 0; r < 4; ++r) {
            int row = rbase + r;
            if (row < rm) {
                int hrow = rowSlot[row];
                #pragma unroll
                for (int n = 0; n < 2; ++n) {
                    float v1 = acc1[m][n][r], v3 = acc3[m][n][r];
                    float hv = (v1 / (1.0f + __expf(-v1))) * v3;
                    int col = n0 + wc * 32 + n * 16 + (lane & 15);
                    hbuf[(size_t)hrow * INTER + col] = f2bf(hv);
                }
            }
        }
    }
}

// ---------------- GEMM2: obuf[slot] = h W2 (A LDS dbuf; B depth-2 reg prefetch) ----------------
__global__ __launch_bounds__(256) void kgemm2(
    const unsigned short* __restrict__ hbuf,
    const unsigned short* __restrict__ w2t, const unsigned short* __restrict__ sw2t,
    const int* __restrict__ cnt, const int* __restrict__ slots,
    unsigned short* __restrict__ obuf)
{
    int e = blockIdx.z;
    int m0 = blockIdx.y * 128;
    int n0 = blockIdx.x * 64;
    int n_rows, lbase;
    if (e < 8) { n_rows = cnt[e]; lbase = cnt[8 + e]; } else { n_rows = NT; lbase = 0; }
    if (m0 >= n_rows) return;
    int rm = min(128, n_rows - m0);
    const unsigned short* bp = (e < 8) ? (w2t + (size_t)e * DIM * INTER) : sw2t;

    __shared__ __align__(16) char sA[2][16384];
    __shared__ int rowH[128];

    int tid = threadIdx.x;
    if (tid < 128) {
        int r = m0 + min(tid, rm - 1);
        rowH[tid] = (e < 8) ? slots[lbase + r] : (4096 + r);
    }
    __syncthreads();

    int wid = tid >> 6, lane = tid & 63;
    int wr = wid >> 1, wc = wid & 1;
    int swz_st = (((lane & 7) ^ (lane >> 3)) - (lane & 7)) * 16;

    const char* pA[4];
    #pragma unroll
    for (int q = 0; q < 4; ++q) {
        int row = (q * 4 + wid) * 8 + (lane >> 3);
        pA[q] = (const char*)(hbuf + (size_t)rowH[row] * INTER) + (lane & 7) * 16 + swz_st;
    }
    const char* pB[2];
    #pragma unroll
    for (int n = 0; n < 2; ++n) {
        int nt = (n0 >> 4) + wc * 2 + n;
        pB[n] = (const char*)bp + (size_t)nt * 32768 + lane * 16;
    }

    int loA[2];
    #pragma unroll
    for (int ks = 0; ks < 2; ++ks) {
        int ch = ((ks * 4) + (lane >> 4)) ^ (lane & 7);
        loA[ks] = (wr * 64 + (lane & 15)) * 128 + ch * 16;
    }

    f32x4 acc[4][2];
    #pragma unroll
    for (int m = 0; m < 4; ++m)
        #pragma unroll
        for (int n = 0; n < 2; ++n) acc[m][n] = (f32x4){0.f,0.f,0.f,0.f};

    s16x8 br[2][2][2];

    #pragma unroll
    for (int q = 0; q < 4; ++q) { cp16(pA[q], (char*)sA + (q * 4 + wid) * 1024); pA[q] += 128; }
    #pragma unroll
    for (int n = 0; n < 2; ++n)
        #pragma unroll
        for (int ks = 0; ks < 2; ++ks)
            br[0][n][ks] = *(const s16x8*)(pB[n] + ks * 1024);
    #pragma unroll
    for (int n = 0; n < 2; ++n)
        #pragma unroll
        for (int ks = 0; ks < 2; ++ks)
            br[1][n][ks] = *(const s16x8*)(pB[n] + (2 + ks) * 1024);

    for (int tt = 0; tt < 7; ++tt) {
        #pragma unroll
        for (int half = 0; half < 2; ++half) {
            #pragma unroll
            for (int q = 0; q < 4; ++q) {
                cp16(pA[q], (char*)sA + (half ^ 1) * 16384 + (q * 4 + wid) * 1024);
                pA[q] += 128;
            }
            asm volatile("s_waitcnt vmcnt(8)" ::: "memory");
            __builtin_amdgcn_sched_barrier(0);
            __builtin_amdgcn_s_barrier();
            __builtin_amdgcn_sched_barrier(0);

            #pragma unroll
            for (int ks = 0; ks < 2; ++ks) {
                s16x8 a[4];
                #pragma unroll
                for (int m = 0; m < 4; ++m)
                    a[m] = *(const s16x8*)((const char*)sA + half * 16384 + m * 2048 + loA[ks]);
                #pragma unroll
                for (int n = 0; n < 2; ++n)
                    #pragma unroll
                    for (int m = 0; m < 4; ++m)
                        acc[m][n] = __builtin_amdgcn_mfma_f32_16x16x32_bf16(a[m], br[half][n][ks], acc[m][n], 0, 0, 0);
            }
            #pragma unroll
            for (int n = 0; n < 2; ++n)
                #pragma unroll
                for (int ks = 0; ks < 2; ++ks)
                    br[half][n][ks] = *(const s16x8*)(pB[n] + (half * 2 + 4 + ks) * 1024);
            __builtin_amdgcn_sched_barrier(0);
            __builtin_amdgcn_s_barrier();
            __builtin_amdgcn_sched_barrier(0);
        }
        #pragma unroll
        for (int n = 0; n < 2; ++n) pB[n] += 4096;
    }
    // t=14
    #pragma unroll
    for (int q = 0; q < 4; ++q) cp16(pA[q], (char*)sA + 16384 + (q * 4 + wid) * 1024);
    asm volatile("s_waitcnt vmcnt(8)" ::: "memory");
    __builtin_amdgcn_sched_barrier(0);
    __builtin_amdgcn_s_barrier();
    __builtin_amdgcn_sched_barrier(0);
    #pragma unroll
    for (int ks = 0; ks < 2; ++ks) {
        s16x8 a[4];
        #pragma unroll
        for (int m = 0; m < 4; ++m)
            a[m] = *(const s16x8*)((const char*)sA + m * 2048 + loA[ks]);
        #pragma unroll
        for (int n = 0; n < 2; ++n)
            #pragma unroll
            for (int m = 0; m < 4; ++m)
                acc[m][n] = __builtin_amdgcn_mfma_f32_16x16x32_bf16(a[m], br[0][n][ks], acc[m][n], 0, 0, 0);
    }
    __builtin_amdgcn_sched_barrier(0);
    __builtin_amdgcn_s_barrier();
    __builtin_amdgcn_sched_barrier(0);
    // t=15
    asm volatile("s_waitcnt vmcnt(0)" ::: "memory");
    __builtin_amdgcn_sched_barrier(0);
    __builtin_amdgcn_s_barrier();
    __builtin_amdgcn_sched_barrier(0);
    #pragma unroll
    for (int ks = 0; ks < 2; ++ks) {
        s16x8 a[4];
        #pragma unroll
        for (int m = 0; m < 4; ++m)
            a[m] = *(const s16x8*)((const char*)sA + 16384 + m * 2048 + loA[ks]);
        #pragma unroll
        for (int n = 0; n < 2; ++n)
            #pragma unroll
            for (int m = 0; m < 4; ++m)
                acc[m][n] = __builtin_amdgcn_mfma_f32_16x16x32_bf16(a[m], br[1][n][ks], acc[m][n], 0, 0, 0);
    }

    #pragma unroll
    for (int m = 0; m < 4; ++m) {
        int rbase = wr * 64 + m * 16 + (lane >> 4) * 4;
        #pragma unroll
        for (int r = 0; r < 4; ++r) {
            int row = rbase + r;
            if (row < rm) {
                int orow = rowH[row];
                #pragma unroll
                for (int n = 0; n < 2; ++n) {
                    int col = n0 + wc * 32 + n * 16 + (lane & 15);
                    obuf[(size_t)orow * DIM + col] = f2bf(acc[m][n][r]);
                }
            }
        }
    }
}

// ---------------- combine ----------------
__global__ __launch_bounds__(256) void kcombine(const unsigned short* __restrict__ obuf,
                                                const float2* __restrict__ wts2,
                                                float* __restrict__ out)
{
    int gid = blockIdx.x * 256 + threadIdx.x;
    int t = gid >> 7;
    int d0 = (gid & 127) * 8;
    float2 w = wts2[t];
    u16x8 r0 = *(const u16x8*)&obuf[(size_t)(2 * t)     * DIM + d0];
    u16x8 r1 = *(const u16x8*)&obuf[(size_t)(2 * t + 1) * DIM + d0];
    u16x8 rs = *(const u16x8*)&obuf[(size_t)(4096 + t)  * DIM + d0];
    f32x4 o0, o1;
    #pragma unroll
    for (int j = 0; j < 4; ++j) o0[j] = w.x * bf2f(r0[j]) + w.y * bf2f(r1[j]) + bf2f(rs[j]);
    #pragma unroll
    for (int j = 0; j < 4; ++j) o1[j] = w.x * bf2f(r0[4+j]) + w.y * bf2f(r1[4+j]) + bf2f(rs[4+j]);
    f32x4* dst = (f32x4*)&out[(size_t)t * DIM + d0];
    dst[0] = o0; dst[1] = o1;
}

extern "C" void kernel_launch(void* const* d_in, const int* in_sizes, int n_in,
                              void* d_out, int out_size, void* d_ws, size_t ws_size,
                              hipStream_t stream) {
    const float* x      = (const float*)d_in[0];
    const float* gate_w = (const float*)d_in[1];
    const float* w1     = (const float*)d_in[2];
    const float* w2     = (const float*)d_in[3];
    const float* w3     = (const float*)d_in[4];
    const float* sw1    = (const float*)d_in[5];
    const float* sw2    = (const float*)d_in[6];
    const float* sw3    = (const float*)d_in[7];
    float* out = (float*)d_out;

    if (ws_size < (size_t)WS_NEED) return;

    char* ws = (char*)d_ws;
    int*            cnt      = (int*)(ws + WS_CNT);
    int*            slots    = (int*)(ws + WS_SLOT);
    int*            assign   = (int*)(ws + WS_ASSIGN);
    float*          wts      = (float*)(ws + WS_WT);
    float2*         wts2     = (float2*)(ws + WS_WTS2);
    unsigned short* xb       = (unsigned short*)(ws + WS_XB);
    unsigned short* hbuf     = (unsigned short*)(ws + WS_H);
    unsigned short* w1t      = (unsigned short*)(ws + WS_W1T);
    unsigned short* w3t      = (unsigned short*)(ws + WS_W3T);
    unsigned short* w2t      = (unsigned short*)(ws + WS_W2T);
    unsigned short* sw1t     = (unsigned short*)(ws + WS_SW1T);
    unsigned short* sw3t     = (unsigned short*)(ws + WS_SW3T);
    unsigned short* sw2t     = (unsigned short*)(ws + WS_SW2T);
    unsigned short* obuf     = (unsigned short*)(ws + WS_OBUF);

    kfat1<<<dim3(2816), 256, 0, stream>>>(x, gate_w, w1, w3, sw1, sw3,
                                          w1t, w3t, sw1t, sw3t, assign, wts2, xb);
    kscatter<<<dim3(8), 256, 0, stream>>>(assign, wts2, cnt, slots, wts);
    kfat2<<<dim3(16, 16, 18), 256, 0, stream>>>(xb, w1t, w3t, sw1t, sw3t, cnt, slots, hbuf,
                                                w2, sw2, w2t, sw2t);
    kgemm2<<<dim3(16, 16, 9), 256, 0, stream>>>(hbuf, w2t, sw2t, cnt, slots, obuf);
    kcombine<<<dim3(1024), 256, 0, stream>>>(obuf, wts2, out);
}